// Round 1
// 583.343 us; speedup vs baseline: 1.0795x; 1.0795x over previous
//
#include <hip/hip_runtime.h>
#include <hip/hip_bf16.h>
#include <math.h>

#define Nn 8192
#define Dd 256
#define Uu 128
#define MI 16
#define NJC 8                  // j-chunks (one per wave-strip)
#define JCL (Nn / NJC)         // 1024 j per wave
#define NIT (JCL / 16)         // 64 iterations of 16 j

typedef __attribute__((ext_vector_type(4))) float f32x4;
typedef __attribute__((ext_vector_type(8))) short s16x8;
typedef __attribute__((ext_vector_type(4))) short s16x4;

#define MFMA_K32(a, b, c) __builtin_amdgcn_mfma_f32_16x16x32_bf16((a), (b), (c), 0, 0, 0)

// K=16 bf16 MFMA: C layout (col=l15,row=4q4+r) of the S^T MFMA == B-frag layout
// (col=l15,k=4q4+e) of this op -> P goes register-direct from S to PV.
__device__ __forceinline__ f32x4 mfma_k16(s16x4 a, s16x4 b, f32x4 c){
#if __has_builtin(__builtin_amdgcn_mfma_f32_16x16x16bf16_1k)
  return __builtin_amdgcn_mfma_f32_16x16x16bf16_1k(a, b, c, 0, 0, 0);
#else
  asm("v_mfma_f32_16x16x16_bf16 %0, %1, %2, %0" : "+v"(c) : "v"(a), "v"(b));
  return c;
#endif
}

__device__ __forceinline__ short f2bf(float f){
  unsigned int u = __float_as_uint(f);
  u += 0x7fffu + ((u >> 16) & 1u);           // RNE
  return (short)(u >> 16);
}

__device__ __forceinline__ float waveSum(float v){
  #pragma unroll
  for (int off = 32; off >= 1; off >>= 1) v += __shfl_xor(v, off);
  return v;
}

// x = expmap0(features @ kernel) -> xh (bf16 [N][U]), x2 = tanh(|z|)^2
__global__ __launch_bounds__(128) void k_prep(const float* __restrict__ feat,
                                              const float* __restrict__ kern,
                                              short* __restrict__ xh,
                                              float* __restrict__ x2){
  const int t = threadIdx.x;                  // == u
  const int n0 = blockIdx.x * 16;
  __shared__ float fS[16][Dd];
  __shared__ float red[2][16];
  {
    const f32x4* fg = (const f32x4*)(feat + (size_t)n0 * Dd);
    f32x4* fd = (f32x4*)fS;
    #pragma unroll
    for (int c = 0; c < 8; ++c) fd[c * 128 + t] = fg[c * 128 + t];
  }
  __syncthreads();
  float zz[16];
  #pragma unroll
  for (int r = 0; r < 16; ++r) zz[r] = 0.f;
  for (int dq = 0; dq < 64; ++dq){
    const int d = dq * 4;
    const float k0 = kern[(size_t)(d + 0) * Uu + t];
    const float k1 = kern[(size_t)(d + 1) * Uu + t];
    const float k2 = kern[(size_t)(d + 2) * Uu + t];
    const float k3 = kern[(size_t)(d + 3) * Uu + t];
    #pragma unroll
    for (int r = 0; r < 16; ++r){
      const f32x4 f4 = *(const f32x4*)&fS[r][d];
      zz[r] = fmaf(f4.x, k0, fmaf(f4.y, k1, fmaf(f4.z, k2, fmaf(f4.w, k3, zz[r]))));
    }
  }
  #pragma unroll
  for (int r = 0; r < 16; ++r){
    float v = waveSum(zz[r] * zz[r]);
    if ((t & 63) == 0) red[t >> 6][r] = v;
  }
  __syncthreads();
  #pragma unroll
  for (int r = 0; r < 16; ++r){
    const float ns  = red[0][r] + red[1][r];
    const float nrm = fmaxf(sqrtf(ns), 1e-15f);
    const float th  = tanhf(nrm);
    xh[(size_t)(n0 + r) * Uu + t] = f2bf(zz[r] * (th / nrm));
  }
  if (t < 16){
    const float ns  = red[0][t] + red[1][t];
    const float nrm = fmaxf(sqrtf(ns), 1e-15f);
    const float th  = tanhf(nrm);
    x2[n0 + t] = th * th;
  }
}

// V re-layout: v3[jb][u][jw] = xh[jb*16+jw][u]  (16-j tiles, A-frag loads become
// one base pointer + <=3.5KB immediate offsets in k_attn)
__global__ __launch_bounds__(256) void k_tr(const short* __restrict__ xh,
                                            short* __restrict__ v3){
  const int n0 = (blockIdx.x & 127) * 64;
  const int u0 = (blockIdx.x >> 7) * 64;
  __shared__ short tS[64][72];
  const int r  = threadIdx.x >> 2;
  const int c0 = (threadIdx.x & 3) * 16;
  const short* src = xh + (size_t)(n0 + r) * Uu + u0 + c0;
  *(s16x8*)&tS[r][c0]     = *(const s16x8*)(src);
  *(s16x8*)&tS[r][c0 + 8] = *(const s16x8*)(src + 8);
  __syncthreads();
  s16x8 b0, b1;
  #pragma unroll
  for (int k = 0; k < 8; ++k){ b0[k] = tS[c0 + k][r]; b1[k] = tS[c0 + 8 + k][r]; }
  short* dst = v3 + (size_t)((n0 + c0) >> 4) * (Uu * 16) + (size_t)(u0 + r) * 16;
  *(s16x8*)(dst)     = b0;   // jw 0..7
  *(s16x8*)(dst + 8) = b1;   // jw 8..15
}

__global__ __launch_bounds__(128) void k_bias(const float* __restrict__ bias,
                                              float* __restrict__ bb){
  const int t = threadIdx.x;
  __shared__ float red[2];
  float bv = bias[t];
  float v = waveSum(bv * bv);
  if ((t & 63) == 0) red[t >> 6] = v;
  __syncthreads();
  float n2  = red[0] + red[1];
  float nrm = fmaxf(sqrtf(n2), 1e-15f);
  float th  = tanhf(nrm);
  bb[t] = bv * th / nrm;
  if (t == 0) bb[Uu] = th * th;
}

// Barrier-free attention: each wave owns 16 i-rows x 1024 j's. Per 16-j step:
// S^T (4 K32 MFMA) -> p (VALU) -> pack -> PV (8 K16 MFMA, full 128-u private
// accumulator). No LDS, no cross-wave exchange; 4 waves/block share the j-chunk
// for L1 reuse of K/V tiles. Partial O/l written per chunk (summed in k_out).
__global__ __launch_bounds__(256, 4) void k_attn(const int* __restrict__ adj,
                                                 const short* __restrict__ xh,
                                                 const short* __restrict__ v3,
                                                 const float* __restrict__ x2g,
                                                 float* __restrict__ Opart,
                                                 float* __restrict__ lpart){
  const int t    = threadIdx.x;
  const int lane = t & 63;
  const int wid  = t >> 6;
  const int l15  = lane & 15;
  const int q4   = lane >> 4;
  const int ig   = blockIdx.x >> 3;           // 128 i-groups of 64 rows
  const int jc   = blockIdx.x & 7;            // j-chunk shared by the 4 waves
  const int i0   = ig * 64 + wid * 16;
  const int irow = i0 + l15;
  const int jbase = jc * JCL;

  // Q B-frags in registers for the whole kernel
  s16x8 qf[4];
  {
    const short* qp = xh + (size_t)irow * Uu + q4 * 8;
    #pragma unroll
    for (int kk = 0; kk < 4; ++kk) qf[kk] = *(const s16x8*)(qp + kk * 32);
  }
  const float x2i  = x2g[irow];
  const float Bv   = 1.f - x2i;
  const float Bv2j = Bv * Bv;
  const float nBv2 = -2.f * Bv;

  f32x4 oc[8];
  #pragma unroll
  for (int uc = 0; uc < 8; ++uc) oc[uc] = (f32x4){0.f, 0.f, 0.f, 0.f};
  float lacc = 0.f;

  // diagonal (j==i) only possible in one iteration of one chunk
  const int itDiag = ((i0 >> 10) == jc) ? ((i0 & 1023) >> 4) : -1;

  const int*   ap  = adj + (size_t)irow * Nn + jbase + q4 * 4;
  const short* kp  = xh + (size_t)(jbase + l15) * Uu + q4 * 8;
  const short* vp  = v3 + (size_t)(jbase >> 4) * (Uu * 16) + l15 * 16 + q4 * 4;
  const float* x2p = x2g + jbase + q4 * 4;

  int4 aqC = *(const int4*)(ap);
  int4 aqN = *(const int4*)(ap + 16);

  #pragma unroll 1
  for (int it = 0; it < NIT; ++it){
    const int j0 = jbase + it * 16;
    // adj prefetch 2 iterations ahead (HBM ~900cy); clamp at strip end
    const int4 aq2 = *(const int4*)(ap + (((it < NIT - 2) ? (it + 2) : (NIT - 1)) << 4));
    // K fragments + x2j + V A-frags for this 16-j tile (L1/L2 resident)
    s16x8 kf[4];
    #pragma unroll
    for (int kk = 0; kk < 4; ++kk) kf[kk] = *(const s16x8*)(kp + kk * 32);
    const f32x4 x2j = *(const f32x4*)(x2p);
    s16x4 vf[8];
    #pragma unroll
    for (int uc = 0; uc < 8; ++uc) vf[uc] = *(const s16x4*)(vp + uc * 256);

    // ---- S^T slice: 4 K32 MFMA, lane holds xy for (i=l15, j=j0+4q4+r) ----
    f32x4 s = {0.f, 0.f, 0.f, 0.f};
    s = MFMA_K32(kf[0], qf[0], s);
    s = MFMA_K32(kf[1], qf[1], s);
    s = MFMA_K32(kf[2], qf[2], s);
    s = MFMA_K32(kf[3], qf[3], s);

    // ---- dist -> p = exp(dist) closed form, mask, pack to bf16 B-frag ----
    const int aarr[4] = {aqC.x, aqC.y, aqC.z, aqC.w};
    const bool dg = (it == itDiag);
    s16x4 pb;
    #pragma unroll
    for (int r = 0; r < 4; ++r){
      const float xy  = s[r];
      const float x2v = x2j[r];
      const float Aa  = fmaf(-2.f, xy, 1.f + x2v);
      const float num = fmaf(Aa * Aa, x2i, fmaf(nBv2 * Aa, xy, Bv2j * x2v));
      const float den = fmaf(x2i, x2v, fmaf(-2.f, xy, 1.f));
      const float sq  = sqrtf(fmaxf(num, 0.f));
      const float pd  = fmaxf(den - sq, 1e-30f);
      float p = fminf((den + sq) * __builtin_amdgcn_rcpf(pd), 2.0e7f);
      bool keep = (aarr[r] != 0) && (sq != 0.f);
      if (dg) keep = keep && ((j0 + 4 * q4 + r) != irow);
      p = keep ? p : 0.f;
      lacc += p;
      pb[r] = f2bf(p);
    }

    // ---- O^T += V^T . P^T : 8 K16 MFMA, P direct from registers ----
    #pragma unroll
    for (int uc = 0; uc < 8; ++uc) oc[uc] = mfma_k16(vf[uc], pb, oc[uc]);

    // rotate pointers / prefetch
    kp += 16 * Uu;
    vp += Uu * 16;
    x2p += 16;
    aqC = aqN; aqN = aq2;
    if ((it & 15) == 15) __syncthreads();     // bound wave drift for L1 reuse
  }

  // ---- epilogue: reduce l over q4, store per-chunk partials (no atomics) ----
  lacc += __shfl_xor(lacc, 16);
  lacc += __shfl_xor(lacc, 32);
  if (lane < 16) lpart[(size_t)jc * Nn + i0 + lane] = lacc;
  float* op = Opart + ((size_t)jc * Nn + irow) * Uu + q4 * 4;
  #pragma unroll
  for (int uc = 0; uc < 8; ++uc) *(f32x4*)(op + uc * 16) = oc[uc];
}

// epilogue: sum 8 partials, normalize, mobius matvec rescale, mobius bias add
__global__ __launch_bounds__(256) void k_out(const float* __restrict__ Opart,
                                             const float* __restrict__ lpart,
                                             const float* __restrict__ x2g,
                                             const float* __restrict__ bb,
                                             float* __restrict__ out){
  const int t  = threadIdx.x;
  const int i0 = blockIdx.x * MI;
  const int er = t >> 4;
  const int ec = t & 15;
  float l = 0.f;
  #pragma unroll
  for (int c = 0; c < NJC; ++c) l += lpart[(size_t)c * Nn + i0 + er];
  const float linv = 1.f / fmaxf(l, 1e-30f);
  float mx[8]; float s2 = 0.f;
  #pragma unroll
  for (int k = 0; k < 8; ++k){
    float v = 0.f;
    #pragma unroll
    for (int c = 0; c < NJC; ++c)
      v += Opart[((size_t)c * Nn + i0 + er) * Uu + ec + 16 * k];
    v *= linv;
    mx[k] = v; s2 = fmaf(v, v, s2);
  }
  s2 += __shfl_xor(s2, 1); s2 += __shfl_xor(s2, 2);
  s2 += __shfl_xor(s2, 4); s2 += __shfl_xor(s2, 8);
  const float mx_n = fmaxf(sqrtf(s2), 1e-15f);
  const float x2e  = x2g[i0 + er];
  const float x_n  = fmaxf(sqrtf(x2e), 1e-15f);
  const float xcl  = fminf(x_n, 1.f - 1e-7f);
  const float art  = 0.5f * __logf((1.f + xcl) / (1.f - xcl));
  const float th   = tanhf(mx_n / x_n * art);
  const float rmn  = th / mx_n;
  float o[8], bu[8]; float ob = 0.f;
  #pragma unroll
  for (int k = 0; k < 8; ++k){
    bu[k] = bb[ec + 16 * k];
    o[k]  = mx[k] * rmn;
    ob = fmaf(o[k], bu[k], ob);
  }
  ob += __shfl_xor(ob, 1); ob += __shfl_xor(ob, 2);
  ob += __shfl_xor(ob, 4); ob += __shfl_xor(ob, 8);
  const float o2   = th * th;
  const float b2   = bb[Uu];
  const float cnum = 1.f + 2.f * ob + b2;
  const float cden = fmaf(o2, b2, 1.f + 2.f * ob);
  const float rden = 1.f / fmaxf(cden, 1e-15f);
  const float co   = 1.f - o2;
  #pragma unroll
  for (int k = 0; k < 8; ++k)
    out[(size_t)(i0 + er) * Uu + ec + 16 * k] = (cnum * o[k] + co * bu[k]) * rden;
}

extern "C" void kernel_launch(void* const* d_in, const int* in_sizes, int n_in,
                              void* d_out, int out_size, void* d_ws, size_t ws_size,
                              hipStream_t stream){
  (void)in_sizes; (void)n_in; (void)out_size; (void)ws_size;
  const float* feat = (const float*)d_in[0];
  const int*   adj  = (const int*)d_in[1];
  const float* kern = (const float*)d_in[2];
  const float* bias = (const float*)d_in[3];

  float* Opart = (float*)d_ws;                          // [8][N][U] f32, 33.5 MB
  float* lpart = Opart + (size_t)NJC * Nn * Uu;         // [8][N]
  float* x2    = lpart + (size_t)NJC * Nn;              // [N]
  float* bbw   = x2 + Nn;                               // [U+1] (padded to 132)
  short* xh    = (short*)(bbw + 132);                   // [N][U] bf16, 2 MB
  short* v3    = xh + (size_t)Nn * Uu;                  // [N/16][U][16] bf16, 2 MB

  k_prep<<<Nn / 16, 128, 0, stream>>>(feat, kern, xh, x2);
  k_tr  <<<256, 256, 0, stream>>>(xh, v3);
  k_bias<<<1, 128, 0, stream>>>(bias, bbw);
  k_attn<<<(Nn / 64) * NJC, 256, 0, stream>>>(adj, xh, v3, x2, Opart, lpart);
  k_out <<<Nn / MI, 256, 0, stream>>>(Opart, lpart, x2, bbw, (float*)d_out);
}

// Round 2
// 507.279 us; speedup vs baseline: 1.2413x; 1.1499x over previous
//
#include <hip/hip_runtime.h>
#include <hip/hip_bf16.h>
#include <math.h>

#define Nn 8192
#define Dd 256
#define Uu 128
#define MI 16
#define NJC 8                  // j-chunks (one per block column)
#define JCL (Nn / NJC)         // 1024 j per block
#define NIT (JCL / 16)         // 64 iterations of 16 j

typedef __attribute__((ext_vector_type(4))) float f32x4;
typedef __attribute__((ext_vector_type(8))) short s16x8;
typedef __attribute__((ext_vector_type(4))) short s16x4;

#define MFMA_K32(a, b, c) __builtin_amdgcn_mfma_f32_16x16x32_bf16((a), (b), (c), 0, 0, 0)

// direct-to-LDS 16B/lane copy: LDS dest = uniform base + lane*16, source per-lane
#define GL_LDS(src, dst)                                                              \
  __builtin_amdgcn_global_load_lds(                                                   \
      (const __attribute__((address_space(1))) unsigned int*)(src),                   \
      (__attribute__((address_space(3))) unsigned int*)(dst), 16, 0, 0)

// K=16 bf16 MFMA: C layout (col=l15,row=4q4+r) of the S^T MFMA == B-frag layout
// (col=l15,k=4q4+e) of this op -> P goes register-direct from S to PV.
__device__ __forceinline__ f32x4 mfma_k16(s16x4 a, s16x4 b, f32x4 c){
#if __has_builtin(__builtin_amdgcn_mfma_f32_16x16x16bf16_1k)
  return __builtin_amdgcn_mfma_f32_16x16x16bf16_1k(a, b, c, 0, 0, 0);
#else
  asm("v_mfma_f32_16x16x16_bf16 %0, %1, %2, %0" : "+v"(c) : "v"(a), "v"(b));
  return c;
#endif
}

__device__ __forceinline__ short f2bf(float f){
  unsigned int u = __float_as_uint(f);
  u += 0x7fffu + ((u >> 16) & 1u);           // RNE
  return (short)(u >> 16);
}

__device__ __forceinline__ float waveSum(float v){
  #pragma unroll
  for (int off = 32; off >= 1; off >>= 1) v += __shfl_xor(v, off);
  return v;
}

// x = expmap0(features @ kernel) -> xh (bf16 [N][U]), x2 = tanh(|z|)^2
__global__ __launch_bounds__(128) void k_prep(const float* __restrict__ feat,
                                              const float* __restrict__ kern,
                                              short* __restrict__ xh,
                                              float* __restrict__ x2){
  const int t = threadIdx.x;                  // == u
  const int n0 = blockIdx.x * 16;
  __shared__ float fS[16][Dd];
  __shared__ float red[2][16];
  {
    const f32x4* fg = (const f32x4*)(feat + (size_t)n0 * Dd);
    f32x4* fd = (f32x4*)fS;
    #pragma unroll
    for (int c = 0; c < 8; ++c) fd[c * 128 + t] = fg[c * 128 + t];
  }
  __syncthreads();
  float zz[16];
  #pragma unroll
  for (int r = 0; r < 16; ++r) zz[r] = 0.f;
  for (int dq = 0; dq < 64; ++dq){
    const int d = dq * 4;
    const float k0 = kern[(size_t)(d + 0) * Uu + t];
    const float k1 = kern[(size_t)(d + 1) * Uu + t];
    const float k2 = kern[(size_t)(d + 2) * Uu + t];
    const float k3 = kern[(size_t)(d + 3) * Uu + t];
    #pragma unroll
    for (int r = 0; r < 16; ++r){
      const f32x4 f4 = *(const f32x4*)&fS[r][d];
      zz[r] = fmaf(f4.x, k0, fmaf(f4.y, k1, fmaf(f4.z, k2, fmaf(f4.w, k3, zz[r]))));
    }
  }
  #pragma unroll
  for (int r = 0; r < 16; ++r){
    float v = waveSum(zz[r] * zz[r]);
    if ((t & 63) == 0) red[t >> 6][r] = v;
  }
  __syncthreads();
  #pragma unroll
  for (int r = 0; r < 16; ++r){
    const float ns  = red[0][r] + red[1][r];
    const float nrm = fmaxf(sqrtf(ns), 1e-15f);
    const float th  = tanhf(nrm);
    xh[(size_t)(n0 + r) * Uu + t] = f2bf(zz[r] * (th / nrm));
  }
  if (t < 16){
    const float ns  = red[0][t] + red[1][t];
    const float nrm = fmaxf(sqrtf(ns), 1e-15f);
    const float th  = tanhf(nrm);
    x2[n0 + t] = th * th;
  }
}

// V re-layout: v3[jb][u][jw] = xh[jb*16+jw][u]  (16-j tiles contiguous 4KB)
__global__ __launch_bounds__(256) void k_tr(const short* __restrict__ xh,
                                            short* __restrict__ v3){
  const int n0 = (blockIdx.x & 127) * 64;
  const int u0 = (blockIdx.x >> 7) * 64;
  __shared__ short tS[64][72];
  const int r  = threadIdx.x >> 2;
  const int c0 = (threadIdx.x & 3) * 16;
  const short* src = xh + (size_t)(n0 + r) * Uu + u0 + c0;
  *(s16x8*)&tS[r][c0]     = *(const s16x8*)(src);
  *(s16x8*)&tS[r][c0 + 8] = *(const s16x8*)(src + 8);
  __syncthreads();
  s16x8 b0, b1;
  #pragma unroll
  for (int k = 0; k < 8; ++k){ b0[k] = tS[c0 + k][r]; b1[k] = tS[c0 + 8 + k][r]; }
  short* dst = v3 + (size_t)((n0 + c0) >> 4) * (Uu * 16) + (size_t)(u0 + r) * 16;
  *(s16x8*)(dst)     = b0;   // jw 0..7
  *(s16x8*)(dst + 8) = b1;   // jw 8..15
}

__global__ __launch_bounds__(128) void k_bias(const float* __restrict__ bias,
                                              float* __restrict__ bb){
  const int t = threadIdx.x;
  __shared__ float red[2];
  float bv = bias[t];
  float v = waveSum(bv * bv);
  if ((t & 63) == 0) red[t >> 6] = v;
  __syncthreads();
  float n2  = red[0] + red[1];
  float nrm = fmaxf(sqrtf(n2), 1e-15f);
  float th  = tanhf(nrm);
  bb[t] = bv * th / nrm;
  if (t == 0) bb[Uu] = th * th;
}

// LDS-shared attention: per block, each 16-j tile of K (pre-fragmented layout) and
// V (v3 layout) is staged ONCE via global_load_lds (double-buffered) and consumed
// by all 4 waves -> 3x fewer L1/TA line-requests than per-wave global loads.
// 2-phase schedule: stage(next) -> ds_read(cur) -> compute -> vmcnt(1) -> s_barrier
// (counted vmcnt keeps the 2-ahead adj register prefetch in flight across barriers).
__global__ __launch_bounds__(256, 4) void k_attn(const int* __restrict__ adj,
                                                 const short* __restrict__ xh,
                                                 const short* __restrict__ v3,
                                                 const float* __restrict__ x2g,
                                                 float* __restrict__ Opart,
                                                 float* __restrict__ lpart){
  const int t    = threadIdx.x;
  const int lane = t & 63;
  const int wid  = t >> 6;
  const int l15  = lane & 15;
  const int q4   = lane >> 4;
  const int ig   = blockIdx.x >> 3;           // 128 i-groups of 64 rows
  const int jc   = blockIdx.x & 7;            // j-chunk shared by the 4 waves
  const int i0   = ig * 64 + wid * 16;
  const int irow = i0 + l15;
  const int jbase = jc * JCL;

  __shared__ short kb[2][2048];               // pre-fragmented K tile: [kk][lane][16B]
  __shared__ short vb[2][2048];               // v3 tile: [u][16 j]

  // staging sources (wave wid stages fragment-chunk kk=wid of K, quarter wid of V)
  const char* ksrc = (const char*)xh + (size_t)jbase * 256
                     + (size_t)(lane & 15) * 256 + wid * 64 + (lane >> 4) * 16;
  const char* vsrc = (const char*)v3 + (size_t)jbase * 256 + wid * 1024 + lane * 16;

  // stage tile 0 into buf 0 (earliest possible issue)
  GL_LDS(ksrc, (char*)&kb[0][0] + wid * 1024);
  GL_LDS(vsrc, (char*)&vb[0][0] + wid * 1024);

  // Q B-frags in registers for the whole kernel
  s16x8 qf[4];
  {
    const short* qp = xh + (size_t)irow * Uu + q4 * 8;
    #pragma unroll
    for (int kk = 0; kk < 4; ++kk) qf[kk] = *(const s16x8*)(qp + kk * 32);
  }
  const float x2i  = x2g[irow];
  const float Bv   = 1.f - x2i;
  const float Bv2j = Bv * Bv;
  const float nBv2 = -2.f * Bv;

  f32x4 oc[8];
  #pragma unroll
  for (int uc = 0; uc < 8; ++uc) oc[uc] = (f32x4){0.f, 0.f, 0.f, 0.f};
  float lacc = 0.f;

  // diagonal (j==i) only possible in one iteration of one chunk
  const int itDiag = ((i0 >> 10) == jc) ? ((i0 & 1023) >> 4) : -1;

  const int*   ap  = adj + (size_t)irow * Nn + jbase + q4 * 4;
  const float* x2p = x2g + jbase + q4 * 4;

  int4 aqC = *(const int4*)(ap);
  int4 aqN = *(const int4*)(ap + 16);

  asm volatile("s_waitcnt vmcnt(0)" ::: "memory");
  __builtin_amdgcn_s_barrier();
  __builtin_amdgcn_sched_barrier(0);

  #pragma unroll 1
  for (int it = 0; it < NIT; ++it){
    const int cur = it & 1;
    // ---- stage next tile into the other buffer (oldest vmem ops of this iter) ----
    if (it + 1 < NIT){
      GL_LDS(ksrc + (size_t)(it + 1) * 4096, (char*)&kb[cur ^ 1][0] + wid * 1024);
      GL_LDS(vsrc + (size_t)(it + 1) * 4096, (char*)&vb[cur ^ 1][0] + wid * 1024);
    }
    __builtin_amdgcn_sched_barrier(0);
    // adj prefetch 2 iterations ahead (HBM ~900cy); clamp at strip end
    const int4 aq2 = *(const int4*)(ap + (((it < NIT - 2) ? (it + 2) : (NIT - 1)) << 4));
    const f32x4 x2j = *(const f32x4*)(x2p + it * 16);

    // ---- LDS reads: K frags (bank-floor b128), V frags (bank-floor b64) ----
    s16x8 kf[4];
    #pragma unroll
    for (int kk = 0; kk < 4; ++kk)
      kf[kk] = *(const s16x8*)((const char*)&kb[cur][0] + kk * 1024 + lane * 16);
    s16x4 vf[8];
    #pragma unroll
    for (int uc = 0; uc < 8; ++uc)
      vf[uc] = *(const s16x4*)((const char*)&vb[cur][0] + uc * 512 + l15 * 32 + q4 * 8);

    // ---- S^T slice: 4 K32 MFMA, lane holds xy for (i=l15, j=j0+4q4+r) ----
    f32x4 s = {0.f, 0.f, 0.f, 0.f};
    s = MFMA_K32(kf[0], qf[0], s);
    s = MFMA_K32(kf[1], qf[1], s);
    s = MFMA_K32(kf[2], qf[2], s);
    s = MFMA_K32(kf[3], qf[3], s);

    // ---- dist -> p = exp(dist) closed form, mask, pack to bf16 B-frag ----
    const int aarr[4] = {aqC.x, aqC.y, aqC.z, aqC.w};
    const bool dg = (it == itDiag);
    const int j0 = jbase + it * 16;
    s16x4 pb;
    #pragma unroll
    for (int r = 0; r < 4; ++r){
      const float xy  = s[r];
      const float x2v = x2j[r];
      const float Aa  = fmaf(-2.f, xy, 1.f + x2v);
      const float num = fmaf(Aa * Aa, x2i, fmaf(nBv2 * Aa, xy, Bv2j * x2v));
      const float den = fmaf(x2i, x2v, fmaf(-2.f, xy, 1.f));
      const float sq  = sqrtf(fmaxf(num, 0.f));
      const float pd  = fmaxf(den - sq, 1e-30f);
      float p = fminf((den + sq) * __builtin_amdgcn_rcpf(pd), 2.0e7f);
      bool keep = (aarr[r] != 0) && (sq != 0.f);
      if (dg) keep = keep && ((j0 + 4 * q4 + r) != irow);
      p = keep ? p : 0.f;
      lacc += p;
      pb[r] = f2bf(p);
    }

    // ---- O^T += V^T . P^T : 8 K16 MFMA, P direct from registers ----
    #pragma unroll
    for (int uc = 0; uc < 8; ++uc) oc[uc] = mfma_k16(vf[uc], pb, oc[uc]);

    aqC = aqN; aqN = aq2;
    // stage writes must land before any wave reads buf[cur^1]; allow the newest
    // vmem op (adj prefetch) to stay in flight across the barrier
    asm volatile("s_waitcnt vmcnt(1)" ::: "memory");
    __builtin_amdgcn_s_barrier();
    __builtin_amdgcn_sched_barrier(0);
  }

  // ---- epilogue: reduce l over q4, store per-chunk partials (no atomics) ----
  lacc += __shfl_xor(lacc, 16);
  lacc += __shfl_xor(lacc, 32);
  if (lane < 16) lpart[(size_t)jc * Nn + i0 + lane] = lacc;
  float* op = Opart + ((size_t)jc * Nn + irow) * Uu + q4 * 4;
  #pragma unroll
  for (int uc = 0; uc < 8; ++uc) *(f32x4*)(op + uc * 16) = oc[uc];
}

// epilogue: sum 8 partials, normalize, mobius matvec rescale, mobius bias add
__global__ __launch_bounds__(256) void k_out(const float* __restrict__ Opart,
                                             const float* __restrict__ lpart,
                                             const float* __restrict__ x2g,
                                             const float* __restrict__ bb,
                                             float* __restrict__ out){
  const int t  = threadIdx.x;
  const int i0 = blockIdx.x * MI;
  const int er = t >> 4;
  const int ec = t & 15;
  float l = 0.f;
  #pragma unroll
  for (int c = 0; c < NJC; ++c) l += lpart[(size_t)c * Nn + i0 + er];
  const float linv = 1.f / fmaxf(l, 1e-30f);
  float mx[8]; float s2 = 0.f;
  #pragma unroll
  for (int k = 0; k < 8; ++k){
    float v = 0.f;
    #pragma unroll
    for (int c = 0; c < NJC; ++c)
      v += Opart[((size_t)c * Nn + i0 + er) * Uu + ec + 16 * k];
    v *= linv;
    mx[k] = v; s2 = fmaf(v, v, s2);
  }
  s2 += __shfl_xor(s2, 1); s2 += __shfl_xor(s2, 2);
  s2 += __shfl_xor(s2, 4); s2 += __shfl_xor(s2, 8);
  const float mx_n = fmaxf(sqrtf(s2), 1e-15f);
  const float x2e  = x2g[i0 + er];
  const float x_n  = fmaxf(sqrtf(x2e), 1e-15f);
  const float xcl  = fminf(x_n, 1.f - 1e-7f);
  const float art  = 0.5f * __logf((1.f + xcl) / (1.f - xcl));
  const float th   = tanhf(mx_n / x_n * art);
  const float rmn  = th / mx_n;
  float o[8], bu[8]; float ob = 0.f;
  #pragma unroll
  for (int k = 0; k < 8; ++k){
    bu[k] = bb[ec + 16 * k];
    o[k]  = mx[k] * rmn;
    ob = fmaf(o[k], bu[k], ob);
  }
  ob += __shfl_xor(ob, 1); ob += __shfl_xor(ob, 2);
  ob += __shfl_xor(ob, 4); ob += __shfl_xor(ob, 8);
  const float o2   = th * th;
  const float b2   = bb[Uu];
  const float cnum = 1.f + 2.f * ob + b2;
  const float cden = fmaf(o2, b2, 1.f + 2.f * ob);
  const float rden = 1.f / fmaxf(cden, 1e-15f);
  const float co   = 1.f - o2;
  #pragma unroll
  for (int k = 0; k < 8; ++k)
    out[(size_t)(i0 + er) * Uu + ec + 16 * k] = (cnum * o[k] + co * bu[k]) * rden;
}

extern "C" void kernel_launch(void* const* d_in, const int* in_sizes, int n_in,
                              void* d_out, int out_size, void* d_ws, size_t ws_size,
                              hipStream_t stream){
  (void)in_sizes; (void)n_in; (void)out_size; (void)ws_size;
  const float* feat = (const float*)d_in[0];
  const int*   adj  = (const int*)d_in[1];
  const float* kern = (const float*)d_in[2];
  const float* bias = (const float*)d_in[3];

  float* Opart = (float*)d_ws;                          // [8][N][U] f32, 33.5 MB
  float* lpart = Opart + (size_t)NJC * Nn * Uu;         // [8][N]
  float* x2    = lpart + (size_t)NJC * Nn;              // [N]
  float* bbw   = x2 + Nn;                               // [U+1] (padded to 132)
  short* xh    = (short*)(bbw + 132);                   // [N][U] bf16, 2 MB
  short* v3    = xh + (size_t)Nn * Uu;                  // [N/16][U][16] bf16, 2 MB

  k_prep<<<Nn / 16, 128, 0, stream>>>(feat, kern, xh, x2);
  k_tr  <<<256, 256, 0, stream>>>(xh, v3);
  k_bias<<<1, 128, 0, stream>>>(bias, bbw);
  k_attn<<<(Nn / 64) * NJC, 256, 0, stream>>>(adj, xh, v3, x2, Opart, lpart);
  k_out <<<Nn / MI, 256, 0, stream>>>(Opart, lpart, x2, bbw, (float*)d_out);
}

// Round 3
// 497.865 us; speedup vs baseline: 1.2648x; 1.0189x over previous
//
#include <hip/hip_runtime.h>
#include <hip/hip_bf16.h>
#include <math.h>

#define Nn 8192
#define Dd 256
#define Uu 128
#define MI 16
#define NJC 8                  // j-chunks (one per block column)
#define JCL (Nn / NJC)         // 1024 j per block
#define NIT (JCL / 16)         // 64 iterations of 16 j

typedef __attribute__((ext_vector_type(4))) float f32x4;
typedef __attribute__((ext_vector_type(8))) short s16x8;
typedef __attribute__((ext_vector_type(4))) short s16x4;

#define MFMA_K32(a, b, c) __builtin_amdgcn_mfma_f32_16x16x32_bf16((a), (b), (c), 0, 0, 0)

// direct-to-LDS 16B/lane copy: LDS dest = uniform base + lane*16, source per-lane
#define GL_LDS(src, dst)                                                              \
  __builtin_amdgcn_global_load_lds(                                                   \
      (const __attribute__((address_space(1))) unsigned int*)(src),                   \
      (__attribute__((address_space(3))) unsigned int*)(dst), 16, 0, 0)

// K=16 bf16 MFMA: C layout (col=l15,row=4q4+r) of the S^T MFMA == B-frag layout
// (col=l15,k=4q4+e) of this op -> P goes register-direct from S to PV.
__device__ __forceinline__ f32x4 mfma_k16(s16x4 a, s16x4 b, f32x4 c){
#if __has_builtin(__builtin_amdgcn_mfma_f32_16x16x16bf16_1k)
  return __builtin_amdgcn_mfma_f32_16x16x16bf16_1k(a, b, c, 0, 0, 0);
#else
  asm("v_mfma_f32_16x16x16_bf16 %0, %1, %2, %0" : "+v"(c) : "v"(a), "v"(b));
  return c;
#endif
}

__device__ __forceinline__ short f2bf(float f){
  unsigned int u = __float_as_uint(f);
  u += 0x7fffu + ((u >> 16) & 1u);           // RNE
  return (short)(u >> 16);
}

__device__ __forceinline__ float waveSum(float v){
  #pragma unroll
  for (int off = 32; off >= 1; off >>= 1) v += __shfl_xor(v, off);
  return v;
}

// x = expmap0(features @ kernel) -> xh (bf16 [N][U]), x2 = tanh(|z|)^2,
// v4 (V tiles in conflict-free LDS order [jb][uc][q4][l15][e]); block 0 also
// computes the hyperbolic bias (former k_bias).
__global__ __launch_bounds__(128) void k_prep(const float* __restrict__ feat,
                                              const float* __restrict__ kern,
                                              const float* __restrict__ bias,
                                              short* __restrict__ xh,
                                              short* __restrict__ v4,
                                              float* __restrict__ x2,
                                              float* __restrict__ bb){
  const int t = threadIdx.x;                  // == u
  const int n0 = blockIdx.x * 16;
  __shared__ float fS[16][Dd];
  __shared__ float red[2][16];
  __shared__ float redb[2];
  {
    const f32x4* fg = (const f32x4*)(feat + (size_t)n0 * Dd);
    f32x4* fd = (f32x4*)fS;
    #pragma unroll
    for (int c = 0; c < 8; ++c) fd[c * 128 + t] = fg[c * 128 + t];
  }
  __syncthreads();
  float zz[16];
  #pragma unroll
  for (int r = 0; r < 16; ++r) zz[r] = 0.f;
  for (int dq = 0; dq < 64; ++dq){
    const int d = dq * 4;
    const float k0 = kern[(size_t)(d + 0) * Uu + t];
    const float k1 = kern[(size_t)(d + 1) * Uu + t];
    const float k2 = kern[(size_t)(d + 2) * Uu + t];
    const float k3 = kern[(size_t)(d + 3) * Uu + t];
    #pragma unroll
    for (int r = 0; r < 16; ++r){
      const f32x4 f4 = *(const f32x4*)&fS[r][d];
      zz[r] = fmaf(f4.x, k0, fmaf(f4.y, k1, fmaf(f4.z, k2, fmaf(f4.w, k3, zz[r]))));
    }
  }
  #pragma unroll
  for (int r = 0; r < 16; ++r){
    float v = waveSum(zz[r] * zz[r]);
    if ((t & 63) == 0) red[t >> 6][r] = v;
  }
  __syncthreads();
  float scl[16];
  #pragma unroll
  for (int r = 0; r < 16; ++r){
    const float ns  = red[0][r] + red[1][r];
    const float nrm = fmaxf(sqrtf(ns), 1e-15f);
    const float th  = tanhf(nrm);
    scl[r] = th / nrm;
    xh[(size_t)(n0 + r) * Uu + t] = f2bf(zz[r] * scl[r]);
  }
  // V tile in k_attn's LDS read order: tile jb=blockIdx.x, element (u=t, jw=4q4+e)
  // at short-offset uc*256 + q4*64 + l15*4 + e
  {
    short* vt = v4 + (size_t)blockIdx.x * 2048 + (size_t)(t >> 4) * 256 + (t & 15) * 4;
    #pragma unroll
    for (int q4w = 0; q4w < 4; ++q4w){
      s16x4 w;
      #pragma unroll
      for (int e = 0; e < 4; ++e) w[e] = f2bf(zz[q4w * 4 + e] * scl[q4w * 4 + e]);
      *(s16x4*)(vt + q4w * 64) = w;
    }
  }
  if (t < 16){
    const float ns  = red[0][t] + red[1][t];
    const float nrm = fmaxf(sqrtf(ns), 1e-15f);
    const float th  = tanhf(nrm);
    x2[n0 + t] = th * th;
  }
  if (blockIdx.x == 0){
    const float bv = bias[t];
    float v = waveSum(bv * bv);
    if ((t & 63) == 0) redb[t >> 6] = v;
    __syncthreads();
    const float n2  = redb[0] + redb[1];
    const float nrm = fmaxf(sqrtf(n2), 1e-15f);
    const float th  = tanhf(nrm);
    bb[t] = bv * th / nrm;
    if (t == 0) bb[Uu] = th * th;
  }
}

// LDS-shared attention, vmcnt-clean: per-iter vmem = {2 stage gl_lds, 1 adj int4
// (3-deep register queue)} only. x2 chunk lives in LDS (staged once), so no
// this-iter vmem dependence exists and the pre-barrier s_waitcnt vmcnt(1) leaves
// the newest adj load in flight ~1.5 iterations -> adj requests stay pipelined.
__global__ __launch_bounds__(256, 4) void k_attn(const int* __restrict__ adj,
                                                 const short* __restrict__ xh,
                                                 const short* __restrict__ v4,
                                                 const float* __restrict__ x2g,
                                                 float* __restrict__ Opart,
                                                 float* __restrict__ lpart){
  const int t    = threadIdx.x;
  const int lane = t & 63;
  const int wid  = t >> 6;
  const int l15  = lane & 15;
  const int q4   = lane >> 4;
  const int ig   = blockIdx.x >> 3;           // 128 i-groups of 64 rows
  const int jc   = blockIdx.x & 7;            // j-chunk shared by the 4 waves
  const int i0   = ig * 64 + wid * 16;
  const int irow = i0 + l15;
  const int jbase = jc * JCL;

  __shared__ __align__(16) short kb[2][2048];   // pre-fragmented K tile [kk][lane*16B]
  __shared__ __align__(16) short vb[2][2048];   // V tile [uc][q4][l15][e]
  __shared__ __align__(16) float x2S[JCL];      // x2 chunk, staged once

  // staging sources (wave wid stages fragment-chunk kk=wid of K, quarter wid of V)
  const char* ksrc = (const char*)xh + (size_t)jbase * 256
                     + (size_t)(lane & 15) * 256 + wid * 64 + (lane >> 4) * 16;
  const char* vsrc = (const char*)v4 + (size_t)jbase * 256 + wid * 1024 + lane * 16;

  // stage tile 0 + x2 chunk into LDS (earliest possible issue)
  GL_LDS(ksrc, (char*)&kb[0][0] + wid * 1024);
  GL_LDS(vsrc, (char*)&vb[0][0] + wid * 1024);
  GL_LDS((const char*)(x2g + jbase) + wid * 1024 + lane * 16, (char*)x2S + wid * 1024);

  // Q B-frags in registers for the whole kernel
  s16x8 qf[4];
  {
    const short* qp = xh + (size_t)irow * Uu + q4 * 8;
    #pragma unroll
    for (int kk = 0; kk < 4; ++kk) qf[kk] = *(const s16x8*)(qp + kk * 32);
  }
  const float x2i  = x2g[irow];
  const float Bv   = 1.f - x2i;
  const float Bv2j = Bv * Bv;
  const float nBv2 = -2.f * Bv;

  f32x4 oc[8];
  #pragma unroll
  for (int uc = 0; uc < 8; ++uc) oc[uc] = (f32x4){0.f, 0.f, 0.f, 0.f};
  float lacc = 0.f;

  // diagonal (j==i) only possible in one iteration of one chunk
  const int itDiag = ((i0 >> 10) == jc) ? ((i0 & 1023) >> 4) : -1;

  const int* ap = adj + (size_t)irow * Nn + jbase + q4 * 4;

  // 3-deep adj register queue (16 cache lines per in-flight instruction)
  int4 aqA = *(const int4*)(ap);
  int4 aqB = *(const int4*)(ap + 16);
  int4 aqC = *(const int4*)(ap + 32);

  asm volatile("s_waitcnt vmcnt(0)" ::: "memory");
  __builtin_amdgcn_s_barrier();
  __builtin_amdgcn_sched_barrier(0);

  #pragma unroll 1
  for (int it = 0; it < NIT; ++it){
    const int cur = it & 1;
    // ---- stage next tile into the other buffer (oldest vmem ops of this iter) ----
    if (it + 1 < NIT){
      GL_LDS(ksrc + (size_t)(it + 1) * 4096, (char*)&kb[cur ^ 1][0] + wid * 1024);
      GL_LDS(vsrc + (size_t)(it + 1) * 4096, (char*)&vb[cur ^ 1][0] + wid * 1024);
    }
    __builtin_amdgcn_sched_barrier(0);
    // adj prefetch 3 iterations ahead; clamp at strip end
    const int4 aqN = *(const int4*)(ap + (((it + 3 < NIT) ? (it + 3) : (NIT - 1)) << 4));

    // ---- LDS reads: K frags (contiguous b128), V frags (contiguous b64), x2 bcast ----
    s16x8 kf[4];
    #pragma unroll
    for (int kk = 0; kk < 4; ++kk)
      kf[kk] = *(const s16x8*)((const char*)&kb[cur][0] + kk * 1024 + lane * 16);
    s16x4 vf[8];
    #pragma unroll
    for (int uc = 0; uc < 8; ++uc)
      vf[uc] = *(const s16x4*)((const char*)&vb[cur][0] + uc * 512 + lane * 8);
    const f32x4 x2j = *(const f32x4*)&x2S[it * 16 + q4 * 4];

    // ---- S^T slice: 4 K32 MFMA, lane holds xy for (i=l15, j=j0+4q4+r) ----
    f32x4 s = {0.f, 0.f, 0.f, 0.f};
    s = MFMA_K32(kf[0], qf[0], s);
    s = MFMA_K32(kf[1], qf[1], s);
    s = MFMA_K32(kf[2], qf[2], s);
    s = MFMA_K32(kf[3], qf[3], s);

    // ---- dist -> p = exp(dist) closed form, mask, pack to bf16 B-frag ----
    const int aarr[4] = {aqA.x, aqA.y, aqA.z, aqA.w};
    const bool dg = (it == itDiag);
    const int j0 = jbase + it * 16;
    s16x4 pb;
    #pragma unroll
    for (int r = 0; r < 4; ++r){
      const float xy  = s[r];
      const float x2v = x2j[r];
      const float Aa  = fmaf(-2.f, xy, 1.f + x2v);
      const float num = fmaf(Aa * Aa, x2i, fmaf(nBv2 * Aa, xy, Bv2j * x2v));
      const float den = fmaf(x2i, x2v, fmaf(-2.f, xy, 1.f));
      const float sq  = sqrtf(fmaxf(num, 0.f));
      const float pd  = fmaxf(den - sq, 1e-30f);
      float p = fminf((den + sq) * __builtin_amdgcn_rcpf(pd), 2.0e7f);
      bool keep = (aarr[r] != 0) && (sq != 0.f);
      if (dg) keep = keep && ((j0 + 4 * q4 + r) != irow);
      p = keep ? p : 0.f;
      lacc += p;
      pb[r] = f2bf(p);
    }

    // ---- O^T += V^T . P^T : 8 K16 MFMA, P direct from registers ----
    #pragma unroll
    for (int uc = 0; uc < 8; ++uc) oc[uc] = mfma_k16(vf[uc], pb, oc[uc]);

    aqA = aqB; aqB = aqC; aqC = aqN;
    // stages must land before any wave reads buf[cur^1]; the newest vmem op
    // (adj queue tail) stays in flight across the barrier
    asm volatile("s_waitcnt vmcnt(1)" ::: "memory");
    __builtin_amdgcn_s_barrier();
    __builtin_amdgcn_sched_barrier(0);
  }

  // ---- epilogue: reduce l over q4, store per-chunk partials (no atomics) ----
  lacc += __shfl_xor(lacc, 16);
  lacc += __shfl_xor(lacc, 32);
  if (lane < 16) lpart[(size_t)jc * Nn + i0 + lane] = lacc;
  float* op = Opart + ((size_t)jc * Nn + irow) * Uu + q4 * 4;
  #pragma unroll
  for (int uc = 0; uc < 8; ++uc) *(f32x4*)(op + uc * 16) = oc[uc];
}

// epilogue: sum 8 partials, normalize, mobius matvec rescale, mobius bias add
__global__ __launch_bounds__(256) void k_out(const float* __restrict__ Opart,
                                             const float* __restrict__ lpart,
                                             const float* __restrict__ x2g,
                                             const float* __restrict__ bb,
                                             float* __restrict__ out){
  const int t  = threadIdx.x;
  const int i0 = blockIdx.x * MI;
  const int er = t >> 4;
  const int ec = t & 15;
  float l = 0.f;
  #pragma unroll
  for (int c = 0; c < NJC; ++c) l += lpart[(size_t)c * Nn + i0 + er];
  const float linv = 1.f / fmaxf(l, 1e-30f);
  float mx[8]; float s2 = 0.f;
  #pragma unroll
  for (int k = 0; k < 8; ++k){
    float v = 0.f;
    #pragma unroll
    for (int c = 0; c < NJC; ++c)
      v += Opart[((size_t)c * Nn + i0 + er) * Uu + ec + 16 * k];
    v *= linv;
    mx[k] = v; s2 = fmaf(v, v, s2);
  }
  s2 += __shfl_xor(s2, 1); s2 += __shfl_xor(s2, 2);
  s2 += __shfl_xor(s2, 4); s2 += __shfl_xor(s2, 8);
  const float mx_n = fmaxf(sqrtf(s2), 1e-15f);
  const float x2e  = x2g[i0 + er];
  const float x_n  = fmaxf(sqrtf(x2e), 1e-15f);
  const float xcl  = fminf(x_n, 1.f - 1e-7f);
  const float art  = 0.5f * __logf((1.f + xcl) / (1.f - xcl));
  const float th   = tanhf(mx_n / x_n * art);
  const float rmn  = th / mx_n;
  float o[8], bu[8]; float ob = 0.f;
  #pragma unroll
  for (int k = 0; k < 8; ++k){
    bu[k] = bb[ec + 16 * k];
    o[k]  = mx[k] * rmn;
    ob = fmaf(o[k], bu[k], ob);
  }
  ob += __shfl_xor(ob, 1); ob += __shfl_xor(ob, 2);
  ob += __shfl_xor(ob, 4); ob += __shfl_xor(ob, 8);
  const float o2   = th * th;
  const float b2   = bb[Uu];
  const float cnum = 1.f + 2.f * ob + b2;
  const float cden = fmaf(o2, b2, 1.f + 2.f * ob);
  const float rden = 1.f / fmaxf(cden, 1e-15f);
  const float co   = 1.f - o2;
  #pragma unroll
  for (int k = 0; k < 8; ++k)
    out[(size_t)(i0 + er) * Uu + ec + 16 * k] = (cnum * o[k] + co * bu[k]) * rden;
}

extern "C" void kernel_launch(void* const* d_in, const int* in_sizes, int n_in,
                              void* d_out, int out_size, void* d_ws, size_t ws_size,
                              hipStream_t stream){
  (void)in_sizes; (void)n_in; (void)out_size; (void)ws_size;
  const float* feat = (const float*)d_in[0];
  const int*   adj  = (const int*)d_in[1];
  const float* kern = (const float*)d_in[2];
  const float* bias = (const float*)d_in[3];

  float* Opart = (float*)d_ws;                          // [8][N][U] f32, 33.5 MB
  float* lpart = Opart + (size_t)NJC * Nn * Uu;         // [8][N]
  float* x2    = lpart + (size_t)NJC * Nn;              // [N]
  float* bbw   = x2 + Nn;                               // [U+1] (padded to 132)
  short* xh    = (short*)(bbw + 132);                   // [N][U] bf16, 2 MB
  short* v4    = xh + (size_t)Nn * Uu;                  // [N/16][2048] bf16, 2 MB

  k_prep<<<Nn / 16, 128, 0, stream>>>(feat, kern, bias, xh, v4, x2, bbw);
  k_attn<<<(Nn / 64) * NJC, 256, 0, stream>>>(adj, xh, v4, x2, Opart, lpart);
  k_out <<<Nn / MI, 256, 0, stream>>>(Opart, lpart, x2, bbw, (float*)d_out);
}

// Round 6
// 472.552 us; speedup vs baseline: 1.3326x; 1.0536x over previous
//
#include <hip/hip_runtime.h>
#include <hip/hip_bf16.h>
#include <math.h>

#define Nn 8192
#define Dd 256
#define Uu 128
#define MI 16
#define NJC 8                  // j-chunks (one per block column)
#define JCL (Nn / NJC)         // 1024 j per block
#define NIT (JCL / 16)         // 64 iterations of 16 j

typedef __attribute__((ext_vector_type(4))) float f32x4;
typedef __attribute__((ext_vector_type(8))) short s16x8;
typedef __attribute__((ext_vector_type(4))) short s16x4;

#define MFMA_K32(a, b, c) __builtin_amdgcn_mfma_f32_16x16x32_bf16((a), (b), (c), 0, 0, 0)

// direct-to-LDS 16B/lane copy: LDS dest = uniform base + lane*16, source per-lane
#define GL_LDS(src, dst)                                                              \
  __builtin_amdgcn_global_load_lds(                                                   \
      (const __attribute__((address_space(1))) unsigned int*)(src),                   \
      (__attribute__((address_space(3))) unsigned int*)(dst), 16, 0, 0)

// K=16 bf16 MFMA: C layout (col=l15,row=4q4+r) of the S^T MFMA == B-frag layout
// (col=l15,k=4q4+e) of this op -> P goes register-direct from S to PV.
__device__ __forceinline__ f32x4 mfma_k16(s16x4 a, s16x4 b, f32x4 c){
#if __has_builtin(__builtin_amdgcn_mfma_f32_16x16x16bf16_1k)
  return __builtin_amdgcn_mfma_f32_16x16x16bf16_1k(a, b, c, 0, 0, 0);
#else
  asm("v_mfma_f32_16x16x16_bf16 %0, %1, %2, %0" : "+v"(c) : "v"(a), "v"(b));
  return c;
#endif
}

__device__ __forceinline__ short f2bf(float f){
  unsigned int u = __float_as_uint(f);
  u += 0x7fffu + ((u >> 16) & 1u);           // RNE
  return (short)(u >> 16);
}

__device__ __forceinline__ float waveSum(float v){
  #pragma unroll
  for (int off = 32; off >= 1; off >>= 1) v += __shfl_xor(v, off);
  return v;
}

// x = expmap0(features @ kernel) -> xh (bf16 [N][U]), x2 = tanh(|z|)^2,
// v4 (V tiles in uc-granular LDS order [jb][uc][q4w][l15][e], R3 layout);
// 256 threads: half-block g owns 8 rows -> serial FMA chain halved, 8 waves/CU.
__global__ __launch_bounds__(256) void k_prep(const float* __restrict__ feat,
                                              const float* __restrict__ kern,
                                              const float* __restrict__ bias,
                                              short* __restrict__ xh,
                                              short* __restrict__ v4,
                                              float* __restrict__ x2,
                                              float* __restrict__ bb){
  const int t = threadIdx.x;
  const int u = t & 127;                      // output column
  const int g = t >> 7;                       // row-half 0/1
  const int n0 = blockIdx.x * 16;
  __shared__ float fS[16][Dd];
  __shared__ float red[4][8];
  __shared__ float redb[4];
  {
    const f32x4* fg = (const f32x4*)(feat + (size_t)n0 * Dd);
    f32x4* fd = (f32x4*)fS;
    #pragma unroll
    for (int c = 0; c < 4; ++c) fd[c * 256 + t] = fg[c * 256 + t];
  }
  __syncthreads();
  float zz[8];
  #pragma unroll
  for (int r = 0; r < 8; ++r) zz[r] = 0.f;
  for (int dq = 0; dq < 64; ++dq){
    const int d = dq * 4;
    const float k0 = kern[(size_t)(d + 0) * Uu + u];
    const float k1 = kern[(size_t)(d + 1) * Uu + u];
    const float k2 = kern[(size_t)(d + 2) * Uu + u];
    const float k3 = kern[(size_t)(d + 3) * Uu + u];
    #pragma unroll
    for (int r = 0; r < 8; ++r){
      const f32x4 f4 = *(const f32x4*)&fS[g * 8 + r][d];
      zz[r] = fmaf(f4.x, k0, fmaf(f4.y, k1, fmaf(f4.z, k2, fmaf(f4.w, k3, zz[r]))));
    }
  }
  // waves 0,1 hold g=0 (rows 0-7); waves 2,3 hold g=1 (rows 8-15)
  #pragma unroll
  for (int r = 0; r < 8; ++r){
    float v = waveSum(zz[r] * zz[r]);
    if ((t & 63) == 0) red[t >> 6][r] = v;
  }
  __syncthreads();
  float scl[8];
  #pragma unroll
  for (int r = 0; r < 8; ++r){
    const float ns  = (g == 0) ? (red[0][r] + red[1][r]) : (red[2][r] + red[3][r]);
    const float nrm = fmaxf(sqrtf(ns), 1e-15f);
    const float th  = tanhf(nrm);
    scl[r] = th / nrm;
    xh[(size_t)(n0 + g * 8 + r) * Uu + u] = f2bf(zz[r] * scl[r]);
  }
  // v4 element (u, jw=4*q4w+e) at short-offset uc*256 + q4w*64 + l15*4 + e;
  // this thread owns jw = g*8 .. g*8+7 -> q4w = 2g + {0,1}, rr = jw - 8g
  {
    short* vt = v4 + (size_t)blockIdx.x * 2048 + (size_t)(u >> 4) * 256 + (u & 15) * 4;
    #pragma unroll
    for (int qq = 0; qq < 2; ++qq){
      s16x4 w;
      #pragma unroll
      for (int e = 0; e < 4; ++e) w[e] = f2bf(zz[qq * 4 + e] * scl[qq * 4 + e]);
      *(s16x4*)(vt + (g * 2 + qq) * 64) = w;
    }
  }
  if (t < 16){
    const float ns  = (t < 8) ? (red[0][t] + red[1][t]) : (red[2][t - 8] + red[3][t - 8]);
    const float nrm = fmaxf(sqrtf(ns), 1e-15f);
    const float th  = tanhf(nrm);
    x2[n0 + t] = th * th;
  }
  if (blockIdx.x == 0){
    const float bv = (t < 128) ? bias[t] : 0.f;
    float v = waveSum(bv * bv);
    if ((t & 63) == 0) redb[t >> 6] = v;
    __syncthreads();
    const float n2  = redb[0] + redb[1] + redb[2] + redb[3];
    const float nrm = fmaxf(sqrtf(n2), 1e-15f);
    const float th  = tanhf(nrm);
    if (t < 128) bb[t] = bv * th / nrm;
    if (t == 0) bb[Uu] = th * th;
  }
}

// LDS-shared attention (R3-verbatim structure, known-good): per-iter vmem =
// {2 stage gl_lds, 1 adj int4 (3-deep register queue)}. x2 chunk staged once in
// LDS; pre-barrier s_waitcnt vmcnt(1) leaves the newest adj load in flight.
__global__ __launch_bounds__(256, 4) void k_attn(const int* __restrict__ adj,
                                                 const short* __restrict__ xh,
                                                 const short* __restrict__ v4,
                                                 const float* __restrict__ x2g,
                                                 float* __restrict__ Opart,
                                                 float* __restrict__ lpart){
  const int t    = threadIdx.x;
  const int lane = t & 63;
  const int wid  = t >> 6;
  const int l15  = lane & 15;
  const int q4   = lane >> 4;
  const int ig   = blockIdx.x >> 3;           // 128 i-groups of 64 rows
  const int jc   = blockIdx.x & 7;            // j-chunk shared by the 4 waves
  const int i0   = ig * 64 + wid * 16;
  const int irow = i0 + l15;
  const int jbase = jc * JCL;

  __shared__ __align__(16) short kb[2][2048];   // pre-fragmented K tile [kk][lane*16B]
  __shared__ __align__(16) short vb[2][2048];   // V tile [uc][q4][l15][e]
  __shared__ __align__(16) float x2S[JCL];      // x2 chunk, staged once

  // staging sources (wave wid stages fragment-chunk kk=wid of K, quarter wid of V)
  const char* ksrc = (const char*)xh + (size_t)jbase * 256
                     + (size_t)(lane & 15) * 256 + wid * 64 + (lane >> 4) * 16;
  const char* vsrc = (const char*)v4 + (size_t)jbase * 256 + wid * 1024 + lane * 16;

  // stage tile 0 + x2 chunk into LDS (earliest possible issue)
  GL_LDS(ksrc, (char*)&kb[0][0] + wid * 1024);
  GL_LDS(vsrc, (char*)&vb[0][0] + wid * 1024);
  GL_LDS((const char*)(x2g + jbase) + wid * 1024 + lane * 16, (char*)x2S + wid * 1024);

  // Q B-frags in registers for the whole kernel
  s16x8 qf[4];
  {
    const short* qp = xh + (size_t)irow * Uu + q4 * 8;
    #pragma unroll
    for (int kk = 0; kk < 4; ++kk) qf[kk] = *(const s16x8*)(qp + kk * 32);
  }
  const float x2i  = x2g[irow];
  const float Bv   = 1.f - x2i;
  const float Bv2j = Bv * Bv;
  const float nBv2 = -2.f * Bv;

  f32x4 oc[8];
  #pragma unroll
  for (int uc = 0; uc < 8; ++uc) oc[uc] = (f32x4){0.f, 0.f, 0.f, 0.f};
  float lacc = 0.f;

  // diagonal (j==i) only possible in one iteration of one chunk
  const int itDiag = ((i0 >> 10) == jc) ? ((i0 & 1023) >> 4) : -1;

  const int* ap = adj + (size_t)irow * Nn + jbase + q4 * 4;

  // 3-deep adj register queue (16 cache lines per in-flight instruction)
  int4 aqA = *(const int4*)(ap);
  int4 aqB = *(const int4*)(ap + 16);
  int4 aqC = *(const int4*)(ap + 32);

  asm volatile("s_waitcnt vmcnt(0)" ::: "memory");
  __builtin_amdgcn_s_barrier();
  __builtin_amdgcn_sched_barrier(0);

  #pragma unroll 1
  for (int it = 0; it < NIT; ++it){
    const int cur = it & 1;
    // ---- stage next tile into the other buffer (oldest vmem ops of this iter) ----
    if (it + 1 < NIT){
      GL_LDS(ksrc + (size_t)(it + 1) * 4096, (char*)&kb[cur ^ 1][0] + wid * 1024);
      GL_LDS(vsrc + (size_t)(it + 1) * 4096, (char*)&vb[cur ^ 1][0] + wid * 1024);
    }
    __builtin_amdgcn_sched_barrier(0);
    // adj prefetch 3 iterations ahead; clamp at strip end
    const int4 aqN = *(const int4*)(ap + (((it + 3 < NIT) ? (it + 3) : (NIT - 1)) << 4));

    // ---- LDS reads: K frags 4x b128, V frags 8x b64, x2 broadcast ----
    s16x8 kf[4];
    #pragma unroll
    for (int kk = 0; kk < 4; ++kk)
      kf[kk] = *(const s16x8*)((const char*)&kb[cur][0] + kk * 1024 + lane * 16);
    s16x4 vf[8];
    #pragma unroll
    for (int uc = 0; uc < 8; ++uc)
      vf[uc] = *(const s16x4*)((const char*)&vb[cur][0] + uc * 512 + lane * 8);
    const f32x4 x2j = *(const f32x4*)&x2S[it * 16 + q4 * 4];

    // ---- S^T slice: 4 K32 MFMA, lane holds xy for (i=l15, j=j0+4q4+r) ----
    f32x4 s = {0.f, 0.f, 0.f, 0.f};
    s = MFMA_K32(kf[0], qf[0], s);
    s = MFMA_K32(kf[1], qf[1], s);
    s = MFMA_K32(kf[2], qf[2], s);
    s = MFMA_K32(kf[3], qf[3], s);

    // ---- dist -> p = exp(dist) closed form, mask, pack to bf16 B-frag ----
    const int aarr[4] = {aqA.x, aqA.y, aqA.z, aqA.w};
    const bool dg = (it == itDiag);
    const int j0 = jbase + it * 16;
    s16x4 pb;
    #pragma unroll
    for (int r = 0; r < 4; ++r){
      const float xy  = s[r];
      const float x2v = x2j[r];
      const float Aa  = fmaf(-2.f, xy, 1.f + x2v);
      const float num = fmaf(Aa * Aa, x2i, fmaf(nBv2 * Aa, xy, Bv2j * x2v));
      const float den = fmaf(x2i, x2v, fmaf(-2.f, xy, 1.f));
      const float sq  = __builtin_amdgcn_sqrtf(fmaxf(num, 0.f));
      const float pd  = fmaxf(den - sq, 1e-30f);
      float p = fminf((den + sq) * __builtin_amdgcn_rcpf(pd), 2.0e7f);
      bool keep = (aarr[r] != 0) && (sq != 0.f);
      if (dg) keep = keep && ((j0 + 4 * q4 + r) != irow);
      p = keep ? p : 0.f;
      lacc += p;
      pb[r] = f2bf(p);
    }

    // ---- O^T += V^T . P^T : 8 K16 MFMA, P direct from registers ----
    #pragma unroll
    for (int uc = 0; uc < 8; ++uc) oc[uc] = mfma_k16(vf[uc], pb, oc[uc]);

    aqA = aqB; aqB = aqC; aqC = aqN;
    // stages must land before any wave reads buf[cur^1]; the newest vmem op
    // (adj queue tail) stays in flight across the barrier
    asm volatile("s_waitcnt vmcnt(1)" ::: "memory");
    __builtin_amdgcn_s_barrier();
    __builtin_amdgcn_sched_barrier(0);
  }

  // ---- epilogue: reduce l over q4, store per-chunk partials (no atomics) ----
  lacc += __shfl_xor(lacc, 16);
  lacc += __shfl_xor(lacc, 32);
  if (lane < 16) lpart[(size_t)jc * Nn + i0 + lane] = lacc;
  float* op = Opart + ((size_t)jc * Nn + irow) * Uu + q4 * 4;
  #pragma unroll
  for (int uc = 0; uc < 8; ++uc) *(f32x4*)(op + uc * 16) = oc[uc];
}

// epilogue: sum 8 partials, normalize, mobius matvec rescale, mobius bias add
__global__ __launch_bounds__(256) void k_out(const float* __restrict__ Opart,
                                             const float* __restrict__ lpart,
                                             const float* __restrict__ x2g,
                                             const float* __restrict__ bb,
                                             float* __restrict__ out){
  const int t  = threadIdx.x;
  const int i0 = blockIdx.x * MI;
  const int er = t >> 4;
  const int ec = t & 15;
  float l = 0.f;
  #pragma unroll
  for (int c = 0; c < NJC; ++c) l += lpart[(size_t)c * Nn + i0 + er];
  const float linv = 1.f / fmaxf(l, 1e-30f);
  float mx[8]; float s2 = 0.f;
  #pragma unroll
  for (int k = 0; k < 8; ++k){
    float v = 0.f;
    #pragma unroll
    for (int c = 0; c < NJC; ++c)
      v += Opart[((size_t)c * Nn + i0 + er) * Uu + ec + 16 * k];
    v *= linv;
    mx[k] = v; s2 = fmaf(v, v, s2);
  }
  s2 += __shfl_xor(s2, 1); s2 += __shfl_xor(s2, 2);
  s2 += __shfl_xor(s2, 4); s2 += __shfl_xor(s2, 8);
  const float mx_n = fmaxf(sqrtf(s2), 1e-15f);
  const float x2e  = x2g[i0 + er];
  const float x_n  = fmaxf(sqrtf(x2e), 1e-15f);
  const float xcl  = fminf(x_n, 1.f - 1e-7f);
  const float art  = 0.5f * __logf((1.f + xcl) / (1.f - xcl));
  const float th   = tanhf(mx_n / x_n * art);
  const float rmn  = th / mx_n;
  float o[8], bu[8]; float ob = 0.f;
  #pragma unroll
  for (int k = 0; k < 8; ++k){
    bu[k] = bb[ec + 16 * k];
    o[k]  = mx[k] * rmn;
    ob = fmaf(o[k], bu[k], ob);
  }
  ob += __shfl_xor(ob, 1); ob += __shfl_xor(ob, 2);
  ob += __shfl_xor(ob, 4); ob += __shfl_xor(ob, 8);
  const float o2   = th * th;
  const float b2   = bb[Uu];
  const float cnum = 1.f + 2.f * ob + b2;
  const float cden = fmaf(o2, b2, 1.f + 2.f * ob);
  const float rden = 1.f / fmaxf(cden, 1e-15f);
  const float co   = 1.f - o2;
  #pragma unroll
  for (int k = 0; k < 8; ++k)
    out[(size_t)(i0 + er) * Uu + ec + 16 * k] = (cnum * o[k] + co * bu[k]) * rden;
}

extern "C" void kernel_launch(void* const* d_in, const int* in_sizes, int n_in,
                              void* d_out, int out_size, void* d_ws, size_t ws_size,
                              hipStream_t stream){
  (void)in_sizes; (void)n_in; (void)out_size; (void)ws_size;
  const float* feat = (const float*)d_in[0];
  const int*   adj  = (const int*)d_in[1];
  const float* kern = (const float*)d_in[2];
  const float* bias = (const float*)d_in[3];

  float* Opart = (float*)d_ws;                          // [8][N][U] f32, 33.5 MB
  float* lpart = Opart + (size_t)NJC * Nn * Uu;         // [8][N]
  float* x2    = lpart + (size_t)NJC * Nn;              // [N]
  float* bbw   = x2 + Nn;                               // [U+1] (padded to 132)
  short* xh    = (short*)(bbw + 132);                   // [N][U] bf16, 2 MB
  short* v4    = xh + (size_t)Nn * Uu;                  // [N/16][2048] bf16, 2 MB

  k_prep<<<Nn / 16, 256, 0, stream>>>(feat, kern, bias, xh, v4, x2, bbw);
  k_attn<<<(Nn / 64) * NJC, 256, 0, stream>>>(adj, xh, v4, x2, Opart, lpart);
  k_out <<<Nn / MI, 256, 0, stream>>>(Opart, lpart, x2, bbw, (float*)d_out);
}

// Round 7
// 467.434 us; speedup vs baseline: 1.3471x; 1.0109x over previous
//
#include <hip/hip_runtime.h>
#include <hip/hip_bf16.h>
#include <math.h>

#define Nn 8192
#define Dd 256
#define Uu 128
#define MI 16
#define NJC 8                  // j-chunks (one per block column)
#define JCL (Nn / NJC)         // 1024 j per block
#define NIT (JCL / 16)         // 64 iterations of 16 j

typedef __attribute__((ext_vector_type(4))) float f32x4;
typedef __attribute__((ext_vector_type(8))) short s16x8;
typedef __attribute__((ext_vector_type(4))) short s16x4;

#define MFMA_K32(a, b, c) __builtin_amdgcn_mfma_f32_16x16x32_bf16((a), (b), (c), 0, 0, 0)

// direct-to-LDS 16B/lane copy: LDS dest = uniform base + lane*16, source per-lane
#define GL_LDS(src, dst)                                                              \
  __builtin_amdgcn_global_load_lds(                                                   \
      (const __attribute__((address_space(1))) unsigned int*)(src),                   \
      (__attribute__((address_space(3))) unsigned int*)(dst), 16, 0, 0)

// K=16 bf16 MFMA: C layout (col=l15,row=4q4+r) of the S^T MFMA == B-frag layout
// (col=l15,k=4q4+e) of this op -> P goes register-direct from S to PV.
__device__ __forceinline__ f32x4 mfma_k16(s16x4 a, s16x4 b, f32x4 c){
#if __has_builtin(__builtin_amdgcn_mfma_f32_16x16x16bf16_1k)
  return __builtin_amdgcn_mfma_f32_16x16x16bf16_1k(a, b, c, 0, 0, 0);
#else
  asm("v_mfma_f32_16x16x16_bf16 %0, %1, %2, %0" : "+v"(c) : "v"(a), "v"(b));
  return c;
#endif
}

__device__ __forceinline__ short f2bf(float f){
  unsigned int u = __float_as_uint(f);
  u += 0x7fffu + ((u >> 16) & 1u);           // RNE
  return (short)(u >> 16);
}

__device__ __forceinline__ float waveSum(float v){
  #pragma unroll
  for (int off = 32; off >= 1; off >>= 1) v += __shfl_xor(v, off);
  return v;
}

// x = expmap0(features @ kernel) -> xh (bf16 [N][U]), x2 = tanh(|z|)^2,
// v4 (V tiles in uc-granular LDS order [jb][uc][q4w][l15][e]);
// 256 threads: half-block g owns 8 rows -> serial FMA chain halved, 8 waves/CU.
__global__ __launch_bounds__(256) void k_prep(const float* __restrict__ feat,
                                              const float* __restrict__ kern,
                                              const float* __restrict__ bias,
                                              short* __restrict__ xh,
                                              short* __restrict__ v4,
                                              float* __restrict__ x2,
                                              float* __restrict__ bb){
  const int t = threadIdx.x;
  const int u = t & 127;                      // output column
  const int g = t >> 7;                       // row-half 0/1
  const int n0 = blockIdx.x * 16;
  __shared__ float fS[16][Dd];
  __shared__ float red[4][8];
  __shared__ float redb[4];
  {
    const f32x4* fg = (const f32x4*)(feat + (size_t)n0 * Dd);
    f32x4* fd = (f32x4*)fS;
    #pragma unroll
    for (int c = 0; c < 4; ++c) fd[c * 256 + t] = fg[c * 256 + t];
  }
  __syncthreads();
  float zz[8];
  #pragma unroll
  for (int r = 0; r < 8; ++r) zz[r] = 0.f;
  for (int dq = 0; dq < 64; ++dq){
    const int d = dq * 4;
    const float k0 = kern[(size_t)(d + 0) * Uu + u];
    const float k1 = kern[(size_t)(d + 1) * Uu + u];
    const float k2 = kern[(size_t)(d + 2) * Uu + u];
    const float k3 = kern[(size_t)(d + 3) * Uu + u];
    #pragma unroll
    for (int r = 0; r < 8; ++r){
      const f32x4 f4 = *(const f32x4*)&fS[g * 8 + r][d];
      zz[r] = fmaf(f4.x, k0, fmaf(f4.y, k1, fmaf(f4.z, k2, fmaf(f4.w, k3, zz[r]))));
    }
  }
  // waves 0,1 hold g=0 (rows 0-7); waves 2,3 hold g=1 (rows 8-15)
  #pragma unroll
  for (int r = 0; r < 8; ++r){
    float v = waveSum(zz[r] * zz[r]);
    if ((t & 63) == 0) red[t >> 6][r] = v;
  }
  __syncthreads();
  float scl[8];
  #pragma unroll
  for (int r = 0; r < 8; ++r){
    const float ns  = (g == 0) ? (red[0][r] + red[1][r]) : (red[2][r] + red[3][r]);
    const float nrm = fmaxf(sqrtf(ns), 1e-15f);
    const float th  = tanhf(nrm);
    scl[r] = th / nrm;
    xh[(size_t)(n0 + g * 8 + r) * Uu + u] = f2bf(zz[r] * scl[r]);
  }
  // v4 element (u, jw=4*q4w+e) at short-offset uc*256 + q4w*64 + l15*4 + e;
  // this thread owns jw = g*8 .. g*8+7 -> q4w = 2g + {0,1}
  {
    short* vt = v4 + (size_t)blockIdx.x * 2048 + (size_t)(u >> 4) * 256 + (u & 15) * 4;
    #pragma unroll
    for (int qq = 0; qq < 2; ++qq){
      s16x4 w;
      #pragma unroll
      for (int e = 0; e < 4; ++e) w[e] = f2bf(zz[qq * 4 + e] * scl[qq * 4 + e]);
      *(s16x4*)(vt + (g * 2 + qq) * 64) = w;
    }
  }
  if (t < 16){
    const float ns  = (t < 8) ? (red[0][t] + red[1][t]) : (red[2][t - 8] + red[3][t - 8]);
    const float nrm = fmaxf(sqrtf(ns), 1e-15f);
    const float th  = tanhf(nrm);
    x2[n0 + t] = th * th;
  }
  if (blockIdx.x == 0){
    const float bv = (t < 128) ? bias[t] : 0.f;
    float v = waveSum(bv * bv);
    if ((t & 63) == 0) redb[t >> 6] = v;
    __syncthreads();
    const float n2  = redb[0] + redb[1] + redb[2] + redb[3];
    const float nrm = fmaxf(sqrtf(n2), 1e-15f);
    const float th  = tanhf(nrm);
    if (t < 128) bb[t] = bv * th / nrm;
    if (t == 0) bb[Uu] = th * th;
  }
}

// LDS-shared attention, software-pipelined one tile deep:
// iter t runs S(t) on the MFMA pipe WHILE p-math(t-1) runs on the VALU pipe and
// PV(t-1) consumes register-carried V frags -- no intra-iter serial S->p->PV
// chain, both pipes fed in every phase. Carried state (sP, vfP[8], x2jP, aqC)
// lives in registers across the barrier. Sync protocol is the proven R6 form:
// stages issued at iter start, vmcnt(0)+s_barrier at iter end (spill-proof).
__global__ __launch_bounds__(256, 4) void k_attn(const int* __restrict__ adj,
                                                 const short* __restrict__ xh,
                                                 const short* __restrict__ v4,
                                                 const float* __restrict__ x2g,
                                                 float* __restrict__ Opart,
                                                 float* __restrict__ lpart){
  const int t    = threadIdx.x;
  const int lane = t & 63;
  const int wid  = t >> 6;
  const int l15  = lane & 15;
  const int q4   = lane >> 4;
  const int ig   = blockIdx.x >> 3;           // 128 i-groups of 64 rows
  const int jc   = blockIdx.x & 7;            // j-chunk shared by the 4 waves
  const int i0   = ig * 64 + wid * 16;
  const int irow = i0 + l15;
  const int jbase = jc * JCL;

  __shared__ __align__(16) short kb[2][2048];   // pre-fragmented K tile [kk][lane*16B]
  __shared__ __align__(16) short vb[2][2048];   // V tile [uc][q4][l15][e]
  __shared__ __align__(16) float x2S[JCL];      // x2 chunk, staged once

  // staging sources (wave wid stages fragment-chunk kk=wid of K, quarter wid of V)
  const char* ksrc = (const char*)xh + (size_t)jbase * 256
                     + (size_t)(lane & 15) * 256 + wid * 64 + (lane >> 4) * 16;
  const char* vsrc = (const char*)v4 + (size_t)jbase * 256 + wid * 1024 + lane * 16;

  // stage tile 0 + x2 chunk into LDS (earliest possible issue)
  GL_LDS(ksrc, (char*)&kb[0][0] + wid * 1024);
  GL_LDS(vsrc, (char*)&vb[0][0] + wid * 1024);
  GL_LDS((const char*)(x2g + jbase) + wid * 1024 + lane * 16, (char*)x2S + wid * 1024);

  // Q B-frags in registers for the whole kernel
  s16x8 qf[4];
  {
    const short* qp = xh + (size_t)irow * Uu + q4 * 8;
    #pragma unroll
    for (int kk = 0; kk < 4; ++kk) qf[kk] = *(const s16x8*)(qp + kk * 32);
  }
  const float x2i  = x2g[irow];
  const float Bv   = 1.f - x2i;
  const float Bv2j = Bv * Bv;
  const float nBv2 = -2.f * Bv;

  f32x4 oc[8];
  #pragma unroll
  for (int uc = 0; uc < 8; ++uc) oc[uc] = (f32x4){0.f, 0.f, 0.f, 0.f};
  float lacc = 0.f;

  // diagonal (j==i) only possible in one tile of one chunk
  const int itDiag = ((i0 >> 10) == jc) ? ((i0 & 1023) >> 4) : -1;

  const int* ap = adj + (size_t)irow * Nn + jbase + q4 * 4;

  // adj queue: aqC = adj(tile processed next), aqL = adj(tile after)
  int4 aqC = *(const int4*)(ap);              // tile 0

  asm volatile("s_waitcnt vmcnt(0)" ::: "memory");
  __builtin_amdgcn_s_barrier();
  __builtin_amdgcn_sched_barrier(0);

  // ---- prologue (pipeline fill): S/vf/x2 for tile 0, stage tile 1 ----
  f32x4 sP;                                   // S result of tile t-1
  s16x4 vfP[8];                               // V frags of tile t-1 (register-carried)
  f32x4 x2jP;                                 // x2 of tile t-1
  int4  aqL = *(const int4*)(ap + 16);        // tile 1
  {
    GL_LDS(ksrc + 4096, (char*)&kb[1][0] + wid * 1024);
    GL_LDS(vsrc + 4096, (char*)&vb[1][0] + wid * 1024);
    s16x8 kf[4];
    #pragma unroll
    for (int kk = 0; kk < 4; ++kk)
      kf[kk] = *(const s16x8*)((const char*)&kb[0][0] + kk * 1024 + lane * 16);
    f32x4 s = {0.f, 0.f, 0.f, 0.f};
    s = MFMA_K32(kf[0], qf[0], s);
    s = MFMA_K32(kf[1], qf[1], s);
    s = MFMA_K32(kf[2], qf[2], s);
    s = MFMA_K32(kf[3], qf[3], s);
    sP = s;
    #pragma unroll
    for (int uc = 0; uc < 8; ++uc)
      vfP[uc] = *(const s16x4*)((const char*)&vb[0][0] + uc * 512 + lane * 8);
    x2jP = *(const f32x4*)&x2S[q4 * 4];
    asm volatile("s_waitcnt vmcnt(0)" ::: "memory");
    __builtin_amdgcn_s_barrier();
    __builtin_amdgcn_sched_barrier(0);
  }

  #pragma unroll 1
  for (int it = 1; it < NIT; ++it){
    const int cur = it & 1;
    // ---- stage tile it+1 into the other buffer (issued first) ----
    if (it + 1 < NIT){
      GL_LDS(ksrc + (size_t)(it + 1) * 4096, (char*)&kb[cur ^ 1][0] + wid * 1024);
      GL_LDS(vsrc + (size_t)(it + 1) * 4096, (char*)&vb[cur ^ 1][0] + wid * 1024);
    }
    __builtin_amdgcn_sched_barrier(0);

    // ---- S(it): 4 K32 MFMA (MFMA pipe; independent of p-math below) ----
    s16x8 kf[4];
    #pragma unroll
    for (int kk = 0; kk < 4; ++kk)
      kf[kk] = *(const s16x8*)((const char*)&kb[cur][0] + kk * 1024 + lane * 16);
    f32x4 sN = {0.f, 0.f, 0.f, 0.f};
    sN = MFMA_K32(kf[0], qf[0], sN);
    sN = MFMA_K32(kf[1], qf[1], sN);
    sN = MFMA_K32(kf[2], qf[2], sN);
    sN = MFMA_K32(kf[3], qf[3], sN);

    // ---- p-math(it-1) on VALU (overlaps S MFMAs), then PV(it-1) ----
    {
      const int aarr[4] = {aqC.x, aqC.y, aqC.z, aqC.w};
      float pv[4];
      #pragma unroll
      for (int r = 0; r < 4; ++r){
        const float xy  = sP[r];
        const float x2v = x2jP[r];
        const float Aa  = fmaf(-2.f, xy, 1.f + x2v);
        const float num = fmaf(Aa * Aa, x2i, fmaf(nBv2 * Aa, xy, Bv2j * x2v));
        const float den = fmaf(x2i, x2v, fmaf(-2.f, xy, 1.f));
        const float sq  = __builtin_amdgcn_sqrtf(fmaxf(num, 0.f));
        const float pd  = fmaxf(den - sq, 1e-30f);
        const float p   = fminf((den + sq) * __builtin_amdgcn_rcpf(pd), 2.0e7f);
        const bool keep = (aarr[r] != 0) && (sq != 0.f);
        pv[r] = keep ? p : 0.f;
      }
      if (it - 1 == itDiag){                  // wave-uniform branch
        const int j0 = jbase + (it - 1) * 16;
        #pragma unroll
        for (int r = 0; r < 4; ++r)
          if ((j0 + 4 * q4 + r) == irow) pv[r] = 0.f;
      }
      lacc += (pv[0] + pv[1]) + (pv[2] + pv[3]);
      s16x4 pb;
      #pragma unroll
      for (int r = 0; r < 4; ++r) pb[r] = f2bf(pv[r]);
      #pragma unroll
      for (int uc = 0; uc < 8; ++uc) oc[uc] = mfma_k16(vfP[uc], pb, oc[uc]);
    }

    // ---- capture carried state for tile it (V into regs before re-stage) ----
    #pragma unroll
    for (int uc = 0; uc < 8; ++uc)
      vfP[uc] = *(const s16x4*)((const char*)&vb[cur][0] + uc * 512 + lane * 8);
    x2jP = *(const f32x4*)&x2S[it * 16 + q4 * 4];
    sP = sN;
    aqC = aqL;
    aqL = *(const int4*)(ap + (((it + 1 < NIT) ? (it + 1) : (NIT - 1)) << 4));

    // spill-proof drain: stages landed before any wave crosses into next tile
    asm volatile("s_waitcnt vmcnt(0)" ::: "memory");
    __builtin_amdgcn_s_barrier();
    __builtin_amdgcn_sched_barrier(0);
  }

  // ---- pipeline drain: p/PV for tile NIT-1 ----
  {
    const int aarr[4] = {aqC.x, aqC.y, aqC.z, aqC.w};
    float pv[4];
    #pragma unroll
    for (int r = 0; r < 4; ++r){
      const float xy  = sP[r];
      const float x2v = x2jP[r];
      const float Aa  = fmaf(-2.f, xy, 1.f + x2v);
      const float num = fmaf(Aa * Aa, x2i, fmaf(nBv2 * Aa, xy, Bv2j * x2v));
      const float den = fmaf(x2i, x2v, fmaf(-2.f, xy, 1.f));
      const float sq  = __builtin_amdgcn_sqrtf(fmaxf(num, 0.f));
      const float pd  = fmaxf(den - sq, 1e-30f);
      const float p   = fminf((den + sq) * __builtin_amdgcn_rcpf(pd), 2.0e7f);
      const bool keep = (aarr[r] != 0) && (sq != 0.f);
      pv[r] = keep ? p : 0.f;
    }
    if (NIT - 1 == itDiag){
      const int j0 = jbase + (NIT - 1) * 16;
      #pragma unroll
      for (int r = 0; r < 4; ++r)
        if ((j0 + 4 * q4 + r) == irow) pv[r] = 0.f;
    }
    lacc += (pv[0] + pv[1]) + (pv[2] + pv[3]);
    s16x4 pb;
    #pragma unroll
    for (int r = 0; r < 4; ++r) pb[r] = f2bf(pv[r]);
    #pragma unroll
    for (int uc = 0; uc < 8; ++uc) oc[uc] = mfma_k16(vfP[uc], pb, oc[uc]);
  }

  // ---- epilogue: reduce l over q4, store per-chunk partials (no atomics) ----
  lacc += __shfl_xor(lacc, 16);
  lacc += __shfl_xor(lacc, 32);
  if (lane < 16) lpart[(size_t)jc * Nn + i0 + lane] = lacc;
  float* op = Opart + ((size_t)jc * Nn + irow) * Uu + q4 * 4;
  #pragma unroll
  for (int uc = 0; uc < 8; ++uc) *(f32x4*)(op + uc * 16) = oc[uc];
}

// epilogue: sum 8 partials, normalize, mobius matvec rescale, mobius bias add
__global__ __launch_bounds__(256) void k_out(const float* __restrict__ Opart,
                                             const float* __restrict__ lpart,
                                             const float* __restrict__ x2g,
                                             const float* __restrict__ bb,
                                             float* __restrict__ out){
  const int t  = threadIdx.x;
  const int i0 = blockIdx.x * MI;
  const int er = t >> 4;
  const int ec = t & 15;
  float l = 0.f;
  #pragma unroll
  for (int c = 0; c < NJC; ++c) l += lpart[(size_t)c * Nn + i0 + er];
  const float linv = 1.f / fmaxf(l, 1e-30f);
  float mx[8]; float s2 = 0.f;
  #pragma unroll
  for (int k = 0; k < 8; ++k){
    float v = 0.f;
    #pragma unroll
    for (int c = 0; c < NJC; ++c)
      v += Opart[((size_t)c * Nn + i0 + er) * Uu + ec + 16 * k];
    v *= linv;
    mx[k] = v; s2 = fmaf(v, v, s2);
  }
  s2 += __shfl_xor(s2, 1); s2 += __shfl_xor(s2, 2);
  s2 += __shfl_xor(s2, 4); s2 += __shfl_xor(s2, 8);
  const float mx_n = fmaxf(sqrtf(s2), 1e-15f);
  const float x2e  = x2g[i0 + er];
  const float x_n  = fmaxf(sqrtf(x2e), 1e-15f);
  const float xcl  = fminf(x_n, 1.f - 1e-7f);
  const float art  = 0.5f * __logf((1.f + xcl) / (1.f - xcl));
  const float th   = tanhf(mx_n / x_n * art);
  const float rmn  = th / mx_n;
  float o[8], bu[8]; float ob = 0.f;
  #pragma unroll
  for (int k = 0; k < 8; ++k){
    bu[k] = bb[ec + 16 * k];
    o[k]  = mx[k] * rmn;
    ob = fmaf(o[k], bu[k], ob);
  }
  ob += __shfl_xor(ob, 1); ob += __shfl_xor(ob, 2);
  ob += __shfl_xor(ob, 4); ob += __shfl_xor(ob, 8);
  const float o2   = th * th;
  const float b2   = bb[Uu];
  const float cnum = 1.f + 2.f * ob + b2;
  const float cden = fmaf(o2, b2, 1.f + 2.f * ob);
  const float rden = 1.f / fmaxf(cden, 1e-15f);
  const float co   = 1.f - o2;
  #pragma unroll
  for (int k = 0; k < 8; ++k)
    out[(size_t)(i0 + er) * Uu + ec + 16 * k] = (cnum * o[k] + co * bu[k]) * rden;
}

extern "C" void kernel_launch(void* const* d_in, const int* in_sizes, int n_in,
                              void* d_out, int out_size, void* d_ws, size_t ws_size,
                              hipStream_t stream){
  (void)in_sizes; (void)n_in; (void)out_size; (void)ws_size;
  const float* feat = (const float*)d_in[0];
  const int*   adj  = (const int*)d_in[1];
  const float* kern = (const float*)d_in[2];
  const float* bias = (const float*)d_in[3];

  float* Opart = (float*)d_ws;                          // [8][N][U] f32, 33.5 MB
  float* lpart = Opart + (size_t)NJC * Nn * Uu;         // [8][N]
  float* x2    = lpart + (size_t)NJC * Nn;              // [N]
  float* bbw   = x2 + Nn;                               // [U+1] (padded to 132)
  short* xh    = (short*)(bbw + 132);                   // [N][U] bf16, 2 MB
  short* v4    = xh + (size_t)Nn * Uu;                  // [N/16][2048] bf16, 2 MB

  k_prep<<<Nn / 16, 256, 0, stream>>>(feat, kern, bias, xh, v4, x2, bbw);
  k_attn<<<(Nn / 64) * NJC, 256, 0, stream>>>(adj, xh, v4, x2, Opart, lpart);
  k_out <<<Nn / MI, 256, 0, stream>>>(Opart, lpart, x2, bbw, (float*)d_out);
}

// Round 8
// 459.775 us; speedup vs baseline: 1.3696x; 1.0167x over previous
//
#include <hip/hip_runtime.h>
#include <hip/hip_bf16.h>
#include <math.h>

#define Nn 8192
#define Dd 256
#define Uu 128
#define MI 16
#define NJC 8                  // j-chunks (one per block column)
#define JCL (Nn / NJC)         // 1024 j per block
#define TJ 32                  // j per iteration (2 subtiles of 16)
#define NIT (JCL / TJ)         // 32 iterations

typedef __attribute__((ext_vector_type(4))) float f32x4;
typedef __attribute__((ext_vector_type(8))) short s16x8;
typedef __attribute__((ext_vector_type(4))) short s16x4;

#define MFMA_K32(a, b, c) __builtin_amdgcn_mfma_f32_16x16x32_bf16((a), (b), (c), 0, 0, 0)

// direct-to-LDS 16B/lane copy: LDS dest = uniform base + lane*16, source per-lane
#define GL_LDS(src, dst)                                                              \
  __builtin_amdgcn_global_load_lds(                                                   \
      (const __attribute__((address_space(1))) unsigned int*)(src),                   \
      (__attribute__((address_space(3))) unsigned int*)(dst), 16, 0, 0)

// K=16 bf16 MFMA: C layout (col=l15,row=4q4+r) of the S^T MFMA == B-frag layout
// (col=l15,k=4q4+e) of this op -> P goes register-direct from S to PV.
__device__ __forceinline__ f32x4 mfma_k16(s16x4 a, s16x4 b, f32x4 c){
#if __has_builtin(__builtin_amdgcn_mfma_f32_16x16x16bf16_1k)
  return __builtin_amdgcn_mfma_f32_16x16x16bf16_1k(a, b, c, 0, 0, 0);
#else
  asm("v_mfma_f32_16x16x16_bf16 %0, %1, %2, %0" : "+v"(c) : "v"(a), "v"(b));
  return c;
#endif
}

__device__ __forceinline__ short f2bf(float f){
  unsigned int u = __float_as_uint(f);
  u += 0x7fffu + ((u >> 16) & 1u);           // RNE
  return (short)(u >> 16);
}

__device__ __forceinline__ float waveSum(float v){
  #pragma unroll
  for (int off = 32; off >= 1; off >>= 1) v += __shfl_xor(v, off);
  return v;
}

// x = expmap0(features @ kernel) -> xh (bf16 [N][U]), x2 = tanh(|z|)^2,
// v4 (V tiles in uc-granular LDS order [jb][uc][q4w][l15][e]);
// 256 threads: half-block g owns 8 rows -> serial FMA chain halved, 8 waves/CU.
__global__ __launch_bounds__(256) void k_prep(const float* __restrict__ feat,
                                              const float* __restrict__ kern,
                                              const float* __restrict__ bias,
                                              short* __restrict__ xh,
                                              short* __restrict__ v4,
                                              float* __restrict__ x2,
                                              float* __restrict__ bb){
  const int t = threadIdx.x;
  const int u = t & 127;                      // output column
  const int g = t >> 7;                       // row-half 0/1
  const int n0 = blockIdx.x * 16;
  __shared__ float fS[16][Dd];
  __shared__ float red[4][8];
  __shared__ float redb[4];
  {
    const f32x4* fg = (const f32x4*)(feat + (size_t)n0 * Dd);
    f32x4* fd = (f32x4*)fS;
    #pragma unroll
    for (int c = 0; c < 4; ++c) fd[c * 256 + t] = fg[c * 256 + t];
  }
  __syncthreads();
  float zz[8];
  #pragma unroll
  for (int r = 0; r < 8; ++r) zz[r] = 0.f;
  for (int dq = 0; dq < 64; ++dq){
    const int d = dq * 4;
    const float k0 = kern[(size_t)(d + 0) * Uu + u];
    const float k1 = kern[(size_t)(d + 1) * Uu + u];
    const float k2 = kern[(size_t)(d + 2) * Uu + u];
    const float k3 = kern[(size_t)(d + 3) * Uu + u];
    #pragma unroll
    for (int r = 0; r < 8; ++r){
      const f32x4 f4 = *(const f32x4*)&fS[g * 8 + r][d];
      zz[r] = fmaf(f4.x, k0, fmaf(f4.y, k1, fmaf(f4.z, k2, fmaf(f4.w, k3, zz[r]))));
    }
  }
  // waves 0,1 hold g=0 (rows 0-7); waves 2,3 hold g=1 (rows 8-15)
  #pragma unroll
  for (int r = 0; r < 8; ++r){
    float v = waveSum(zz[r] * zz[r]);
    if ((t & 63) == 0) red[t >> 6][r] = v;
  }
  __syncthreads();
  float scl[8];
  #pragma unroll
  for (int r = 0; r < 8; ++r){
    const float ns  = (g == 0) ? (red[0][r] + red[1][r]) : (red[2][r] + red[3][r]);
    const float nrm = fmaxf(sqrtf(ns), 1e-15f);
    const float th  = tanhf(nrm);
    scl[r] = th / nrm;
    xh[(size_t)(n0 + g * 8 + r) * Uu + u] = f2bf(zz[r] * scl[r]);
  }
  // v4 element (u, jw=4*q4w+e) at short-offset uc*256 + q4w*64 + l15*4 + e;
  // this thread owns jw = g*8 .. g*8+7 -> q4w = 2g + {0,1}
  {
    short* vt = v4 + (size_t)blockIdx.x * 2048 + (size_t)(u >> 4) * 256 + (u & 15) * 4;
    #pragma unroll
    for (int qq = 0; qq < 2; ++qq){
      s16x4 w;
      #pragma unroll
      for (int e = 0; e < 4; ++e) w[e] = f2bf(zz[qq * 4 + e] * scl[qq * 4 + e]);
      *(s16x4*)(vt + (g * 2 + qq) * 64) = w;
    }
  }
  if (t < 16){
    const float ns  = (t < 8) ? (red[0][t] + red[1][t]) : (red[2][t - 8] + red[3][t - 8]);
    const float nrm = fmaxf(sqrtf(ns), 1e-15f);
    const float th  = tanhf(nrm);
    x2[n0 + t] = th * th;
  }
  if (blockIdx.x == 0){
    const float bv = (t < 128) ? bias[t] : 0.f;
    float v = waveSum(bv * bv);
    if ((t & 63) == 0) redb[t >> 6] = v;
    __syncthreads();
    const float n2  = redb[0] + redb[1] + redb[2] + redb[3];
    const float nrm = fmaxf(sqrtf(n2), 1e-15f);
    const float th  = tanhf(nrm);
    if (t < 128) bb[t] = bv * th / nrm;
    if (t == 0) bb[Uu] = th * th;
  }
}

// LDS-shared attention, 32-j tiles: HALVED barrier/drain count vs 16-j (the
// invariant ~6k-cy per-iteration fixed cost across R2-R7 is iteration-granular,
// so amortize it). Serial R6-style body (proven) over two 16-j subtiles.
// Per-iter vmem, pinned order: [4x gl_lds stage(t+1)] then [2x adj int4 (t+2)];
// pre-barrier vmcnt(2) drains the stages and leaves exactly the 2 adj loads in
// flight (2-iteration slack >> HBM latency).
__global__ __launch_bounds__(256, 4) void k_attn(const int* __restrict__ adj,
                                                 const short* __restrict__ xh,
                                                 const short* __restrict__ v4,
                                                 const float* __restrict__ x2g,
                                                 float* __restrict__ Opart,
                                                 float* __restrict__ lpart){
  const int t    = threadIdx.x;
  const int lane = t & 63;
  const int wid  = t >> 6;
  const int l15  = lane & 15;
  const int q4   = lane >> 4;
  const int ig   = blockIdx.x >> 3;           // 128 i-groups of 64 rows
  const int jc   = blockIdx.x & 7;            // j-chunk shared by the 4 waves
  const int i0   = ig * 64 + wid * 16;
  const int irow = i0 + l15;
  const int jbase = jc * JCL;

  __shared__ __align__(16) short kb[2][4096];   // K tile (2 subtiles, frag layout)
  __shared__ __align__(16) short vb[2][4096];   // V tile (2 subtiles, uc layout)
  __shared__ __align__(16) float x2S[JCL];      // x2 chunk, staged once

  // per-wave staging sources (wave wid stages chunk kk=wid / quarter wid)
  const char* ksrcW = (const char*)xh + (size_t)jbase * 256
                      + l15 * 256 + wid * 64 + q4 * 16;
  const char* vsrcW = (const char*)v4 + (size_t)(jbase >> 4) * 4096
                      + wid * 1024 + lane * 16;

  // stage tile 0 (both subtiles) + x2 chunk
  GL_LDS(ksrcW,        (char*)&kb[0][0] + wid * 1024);
  GL_LDS(ksrcW + 4096, (char*)&kb[0][0] + 4096 + wid * 1024);
  GL_LDS(vsrcW,        (char*)&vb[0][0] + wid * 1024);
  GL_LDS(vsrcW + 4096, (char*)&vb[0][0] + 4096 + wid * 1024);
  GL_LDS((const char*)(x2g + jbase) + wid * 1024 + lane * 16, (char*)x2S + wid * 1024);

  // Q B-frags in registers for the whole kernel
  s16x8 qf[4];
  {
    const short* qp = xh + (size_t)irow * Uu + q4 * 8;
    #pragma unroll
    for (int kk = 0; kk < 4; ++kk) qf[kk] = *(const s16x8*)(qp + kk * 32);
  }
  const float x2i  = x2g[irow];
  const float Bv   = 1.f - x2i;
  const float Bv2j = Bv * Bv;
  const float nBv2 = -2.f * Bv;

  f32x4 oc[8];
  #pragma unroll
  for (int uc = 0; uc < 8; ++uc) oc[uc] = (f32x4){0.f, 0.f, 0.f, 0.f};
  float lacc = 0.f;

  // diagonal (j==i): one 32-j tile, one 16-j subtile of it
  const int itDiag = ((i0 >> 10) == jc) ? ((i0 & 1023) >> 5) : -1;
  const int sDiag  = (i0 >> 4) & 1;

  const int* ap = adj + (size_t)irow * Nn + jbase + q4 * 4;

  // 2-deep adj queue of int4 PAIRS (subtile 0/1), loaded 2 tiles ahead
  int4 aqA0 = *(const int4*)(ap);
  int4 aqA1 = *(const int4*)(ap + 16);
  int4 aqB0 = *(const int4*)(ap + 32);
  int4 aqB1 = *(const int4*)(ap + 48);

  asm volatile("s_waitcnt vmcnt(0)" ::: "memory");
  __builtin_amdgcn_s_barrier();
  __builtin_amdgcn_sched_barrier(0);

  #pragma unroll 1
  for (int it = 0; it < NIT; ++it){
    const int cur = it & 1;
    // ---- stage tile it+1 (4 gl_lds, oldest vmem ops of this iter) ----
    if (it + 1 < NIT){
      const size_t o = (size_t)(it + 1) * 8192;
      GL_LDS(ksrcW + o,        (char*)&kb[cur ^ 1][0] + wid * 1024);
      GL_LDS(ksrcW + o + 4096, (char*)&kb[cur ^ 1][0] + 4096 + wid * 1024);
      GL_LDS(vsrcW + o,        (char*)&vb[cur ^ 1][0] + wid * 1024);
      GL_LDS(vsrcW + o + 4096, (char*)&vb[cur ^ 1][0] + 4096 + wid * 1024);
    }
    __builtin_amdgcn_sched_barrier(0);
    // ---- adj prefetch for tile it+2 (the 2 NEWEST vmem ops; clamp at end) ----
    const int itn = (it + 2 < NIT) ? (it + 2) : (NIT - 1);
    const int4 aqN0 = *(const int4*)(ap + itn * 32);
    const int4 aqN1 = *(const int4*)(ap + itn * 32 + 16);
    __builtin_amdgcn_sched_barrier(0);

    // ---- two serial 16-j subtiles ----
    #pragma unroll
    for (int sdx = 0; sdx < 2; ++sdx){
      const char* kbp = (const char*)&kb[cur][0] + sdx * 4096;
      const char* vbp = (const char*)&vb[cur][0] + sdx * 4096;
      s16x8 kf[4];
      #pragma unroll
      for (int kk = 0; kk < 4; ++kk)
        kf[kk] = *(const s16x8*)(kbp + kk * 1024 + lane * 16);
      f32x4 s = {0.f, 0.f, 0.f, 0.f};
      s = MFMA_K32(kf[0], qf[0], s);
      s = MFMA_K32(kf[1], qf[1], s);
      s = MFMA_K32(kf[2], qf[2], s);
      s = MFMA_K32(kf[3], qf[3], s);

      const f32x4 x2j = *(const f32x4*)&x2S[it * TJ + sdx * 16 + q4 * 4];
      const int4  aq  = sdx ? aqA1 : aqA0;
      const int aarr[4] = {aq.x, aq.y, aq.z, aq.w};
      float pv[4];
      #pragma unroll
      for (int r = 0; r < 4; ++r){
        const float xy  = s[r];
        const float x2v = x2j[r];
        const float Aa  = fmaf(-2.f, xy, 1.f + x2v);
        const float num = fmaf(Aa * Aa, x2i, fmaf(nBv2 * Aa, xy, Bv2j * x2v));
        const float den = fmaf(x2i, x2v, fmaf(-2.f, xy, 1.f));
        const float sq  = __builtin_amdgcn_sqrtf(fmaxf(num, 0.f));
        const float pd  = fmaxf(den - sq, 1e-30f);
        const float p   = fminf((den + sq) * __builtin_amdgcn_rcpf(pd), 2.0e7f);
        const bool keep = (aarr[r] != 0) && (sq != 0.f);
        pv[r] = keep ? p : 0.f;
      }
      if (it == itDiag && sdx == sDiag){      // wave-uniform branch
        const int j0 = jbase + it * TJ + sdx * 16;
        #pragma unroll
        for (int r = 0; r < 4; ++r)
          if ((j0 + 4 * q4 + r) == irow) pv[r] = 0.f;
      }
      lacc += (pv[0] + pv[1]) + (pv[2] + pv[3]);
      s16x4 pb;
      #pragma unroll
      for (int r = 0; r < 4; ++r) pb[r] = f2bf(pv[r]);

      s16x4 vf[8];
      #pragma unroll
      for (int uc = 0; uc < 8; ++uc)
        vf[uc] = *(const s16x4*)(vbp + uc * 512 + lane * 8);
      #pragma unroll
      for (int uc = 0; uc < 8; ++uc) oc[uc] = mfma_k16(vf[uc], pb, oc[uc]);
    }

    aqA0 = aqB0; aqA1 = aqB1; aqB0 = aqN0; aqB1 = aqN1;
    // drain the 4 stage gl_lds; leave the 2 adj loads (tile it+2) in flight
    asm volatile("s_waitcnt vmcnt(2)" ::: "memory");
    __builtin_amdgcn_s_barrier();
    __builtin_amdgcn_sched_barrier(0);
  }

  // ---- epilogue: reduce l over q4, store per-chunk partials (no atomics) ----
  lacc += __shfl_xor(lacc, 16);
  lacc += __shfl_xor(lacc, 32);
  if (lane < 16) lpart[(size_t)jc * Nn + i0 + lane] = lacc;
  float* op = Opart + ((size_t)jc * Nn + irow) * Uu + q4 * 4;
  #pragma unroll
  for (int uc = 0; uc < 8; ++uc) *(f32x4*)(op + uc * 16) = oc[uc];
}

// epilogue: sum 8 partials, normalize, mobius matvec rescale, mobius bias add
__global__ __launch_bounds__(256) void k_out(const float* __restrict__ Opart,
                                             const float* __restrict__ lpart,
                                             const float* __restrict__ x2g,
                                             const float* __restrict__ bb,
                                             float* __restrict__ out){
  const int t  = threadIdx.x;
  const int i0 = blockIdx.x * MI;
  const int er = t >> 4;
  const int ec = t & 15;
  float l = 0.f;
  #pragma unroll
  for (int c = 0; c < NJC; ++c) l += lpart[(size_t)c * Nn + i0 + er];
  const float linv = 1.f / fmaxf(l, 1e-30f);
  float mx[8]; float s2 = 0.f;
  #pragma unroll
  for (int k = 0; k < 8; ++k){
    float v = 0.f;
    #pragma unroll
    for (int c = 0; c < NJC; ++c)
      v += Opart[((size_t)c * Nn + i0 + er) * Uu + ec + 16 * k];
    v *= linv;
    mx[k] = v; s2 = fmaf(v, v, s2);
  }
  s2 += __shfl_xor(s2, 1); s2 += __shfl_xor(s2, 2);
  s2 += __shfl_xor(s2, 4); s2 += __shfl_xor(s2, 8);
  const float mx_n = fmaxf(sqrtf(s2), 1e-15f);
  const float x2e  = x2g[i0 + er];
  const float x_n  = fmaxf(sqrtf(x2e), 1e-15f);
  const float xcl  = fminf(x_n, 1.f - 1e-7f);
  const float art  = 0.5f * __logf((1.f + xcl) / (1.f - xcl));
  const float th   = tanhf(mx_n / x_n * art);
  const float rmn  = th / mx_n;
  float o[8], bu[8]; float ob = 0.f;
  #pragma unroll
  for (int k = 0; k < 8; ++k){
    bu[k] = bb[ec + 16 * k];
    o[k]  = mx[k] * rmn;
    ob = fmaf(o[k], bu[k], ob);
  }
  ob += __shfl_xor(ob, 1); ob += __shfl_xor(ob, 2);
  ob += __shfl_xor(ob, 4); ob += __shfl_xor(ob, 8);
  const float o2   = th * th;
  const float b2   = bb[Uu];
  const float cnum = 1.f + 2.f * ob + b2;
  const float cden = fmaf(o2, b2, 1.f + 2.f * ob);
  const float rden = 1.f / fmaxf(cden, 1e-15f);
  const float co   = 1.f - o2;
  #pragma unroll
  for (int k = 0; k < 8; ++k)
    out[(size_t)(i0 + er) * Uu + ec + 16 * k] = (cnum * o[k] + co * bu[k]) * rden;
}

extern "C" void kernel_launch(void* const* d_in, const int* in_sizes, int n_in,
                              void* d_out, int out_size, void* d_ws, size_t ws_size,
                              hipStream_t stream){
  (void)in_sizes; (void)n_in; (void)out_size; (void)ws_size;
  const float* feat = (const float*)d_in[0];
  const int*   adj  = (const int*)d_in[1];
  const float* kern = (const float*)d_in[2];
  const float* bias = (const float*)d_in[3];

  float* Opart = (float*)d_ws;                          // [8][N][U] f32, 33.5 MB
  float* lpart = Opart + (size_t)NJC * Nn * Uu;         // [8][N]
  float* x2    = lpart + (size_t)NJC * Nn;              // [N]
  float* bbw   = x2 + Nn;                               // [U+1] (padded to 132)
  short* xh    = (short*)(bbw + 132);                   // [N][U] bf16, 2 MB
  short* v4    = xh + (size_t)Nn * Uu;                  // [N/16][2048] bf16, 2 MB

  k_prep<<<Nn / 16, 256, 0, stream>>>(feat, kern, bias, xh, v4, x2, bbw);
  k_attn<<<(Nn / 64) * NJC, 256, 0, stream>>>(adj, xh, v4, x2, Opart, lpart);
  k_out <<<Nn / MI, 256, 0, stream>>>(Opart, lpart, x2, bbw, (float*)d_out);
}